// Round 1
// baseline (2680.674 us; speedup 1.0000x reference)
//
#include <hip/hip_runtime.h>
#include <math.h>

#define NHEAD 12
#define DH 64
#define S_LEN 4096
#define B_SZ 2
#define D_MODEL 768
#define FF_DIM 3072
#define WINSZ 128
#define NGLB 32
#define NEGV -1e9f

// ---------------------------------------------------------------------------
// GEMM: out = epilogue(A @ W + bias); A: MxK row-major, W: KxN row-major.
// EPI 0: + resid -> Cout (MxN)
// EPI 1: exact gelu -> Cout (MxN)
// EPI 2: scale then scatter to (B, NH, S, DH) layout (N == 768)
// 128x128 tile, BK=16, 256 threads, 8x8 per thread, fp32.
// ---------------------------------------------------------------------------
template <int EPI>
__global__ __launch_bounds__(256) void gemm_k(
    const float* __restrict__ A, const float* __restrict__ W,
    const float* __restrict__ bias, const float* __restrict__ resid,
    float* __restrict__ Cout, int M, int N, int K, float scale)
{
    __shared__ float As[16][132];
    __shared__ float Bs[16][132];
    const int tid = threadIdx.x;
    const int m0 = blockIdx.y * 128;
    const int n0 = blockIdx.x * 128;
    const int tx = tid & 15;
    const int ty = tid >> 4;

    float acc[8][8];
#pragma unroll
    for (int i = 0; i < 8; ++i)
#pragma unroll
        for (int j = 0; j < 8; ++j) acc[i][j] = 0.f;

    const int a_m = tid >> 4;   // + 16*i
    const int a_k = tid & 15;
    const int b_k = tid >> 7;   // + 2*i
    const int b_n = tid & 127;

    for (int k0 = 0; k0 < K; k0 += 16) {
#pragma unroll
        for (int i = 0; i < 8; ++i)
            As[a_k][a_m + 16 * i] = A[(long)(m0 + a_m + 16 * i) * K + k0 + a_k];
#pragma unroll
        for (int i = 0; i < 8; ++i)
            Bs[b_k + 2 * i][b_n] = W[(long)(k0 + b_k + 2 * i) * N + n0 + b_n];
        __syncthreads();
#pragma unroll
        for (int kk = 0; kk < 16; ++kk) {
            float a[8], b[8];
#pragma unroll
            for (int i = 0; i < 8; ++i) a[i] = As[kk][ty * 8 + i];
#pragma unroll
            for (int j = 0; j < 8; ++j) b[j] = Bs[kk][tx * 8 + j];
#pragma unroll
            for (int i = 0; i < 8; ++i)
#pragma unroll
                for (int j = 0; j < 8; ++j) acc[i][j] += a[i] * b[j];
        }
        __syncthreads();
    }

    const int col = n0 + tx * 8;
    float bsv[8];
#pragma unroll
    for (int j = 0; j < 8; ++j) bsv[j] = bias[col + j];

#pragma unroll
    for (int i = 0; i < 8; ++i) {
        const int m = m0 + ty * 8 + i;
        float v[8];
#pragma unroll
        for (int j = 0; j < 8; ++j) v[j] = acc[i][j] + bsv[j];
        if (EPI == 0) {
            const float4* rp = (const float4*)(resid + (long)m * N + col);
            float4 r0 = rp[0], r1 = rp[1];
            v[0] += r0.x; v[1] += r0.y; v[2] += r0.z; v[3] += r0.w;
            v[4] += r1.x; v[5] += r1.y; v[6] += r1.z; v[7] += r1.w;
            float4* cp = (float4*)(Cout + (long)m * N + col);
            cp[0] = make_float4(v[0], v[1], v[2], v[3]);
            cp[1] = make_float4(v[4], v[5], v[6], v[7]);
        } else if (EPI == 1) {
#pragma unroll
            for (int j = 0; j < 8; ++j)
                v[j] = 0.5f * v[j] * (1.f + erff(v[j] * 0.70710678118654752f));
            float4* cp = (float4*)(Cout + (long)m * N + col);
            cp[0] = make_float4(v[0], v[1], v[2], v[3]);
            cp[1] = make_float4(v[4], v[5], v[6], v[7]);
        } else {
            const int bb = m >> 12;        // m / 4096
            const int s  = m & 4095;
            const int hh = col >> 6;
            const int dh = col & 63;
#pragma unroll
            for (int j = 0; j < 8; ++j) v[j] *= scale;
            float4* cp = (float4*)(Cout +
                ((((long)bb * NHEAD + hh) * S_LEN + s) * DH + dh));
            cp[0] = make_float4(v[0], v[1], v[2], v[3]);
            cp[1] = make_float4(v[4], v[5], v[6], v[7]);
        }
    }
}

// ---------------------------------------------------------------------------
// Band (sliding-window) attention + global-key columns.
// One block per (b, h, chunk). 128 threads, one query row per thread.
// Online softmax over 13 tiles of 32 keys (12 band tiles + 1 global tile).
// Writes ctx in (B, S, NH*DH) layout. Rows s < NG are overwritten later by
// the global-query kernel (stream-ordered).
// ---------------------------------------------------------------------------
__global__ __launch_bounds__(128) void band_attn_k(
    const float* __restrict__ q, const float* __restrict__ k,
    const float* __restrict__ v, const float* __restrict__ am,
    float* __restrict__ ctx)
{
    __shared__ float KV[32 * 64];  // 8 KB, reused for K then V per tile
    const int blk = blockIdx.x;            // B*NH*C = 768
    const int c = blk & 31;
    const int h = (blk >> 5) % NHEAD;
    const int b = blk / (32 * NHEAD);
    const int t = threadIdx.x;             // query row within chunk
    const int s = c * WINSZ + t;

    const float* kh  = k + ((long)b * NHEAD + h) * S_LEN * DH;
    const float* vh  = v + ((long)b * NHEAD + h) * S_LEN * DH;
    const float* amb = am + (long)b * S_LEN;

    float4 qr[16];
    {
        const float4* q4 = (const float4*)(q + (((long)b * NHEAD + h) * S_LEN + s) * DH);
#pragma unroll
        for (int i = 0; i < 16; ++i) qr[i] = q4[i];
    }

    float mrun = -1e30f, lrun = 0.f;
    float4 o[16];
#pragma unroll
    for (int i = 0; i < 16; ++i) o[i] = make_float4(0.f, 0.f, 0.f, 0.f);

    for (int tile = 0; tile < 13; ++tile) {
        const bool glob = (tile == 12);
        const int kbase = glob ? 0 : (c * WINSZ - WINSZ + tile * 32);

        // ---- stage K tile (32 keys x 64) ----
        __syncthreads();
#pragma unroll
        for (int l2 = 0; l2 < 16; ++l2) {
            int e = l2 * 128 + t;
            int j = e >> 6, d = e & 63;
            int kpos = kbase + j;
            float val = 0.f;
            if ((unsigned)kpos < (unsigned)S_LEN) val = kh[(long)kpos * DH + d];
            KV[e] = val;
        }
        __syncthreads();

        // ---- logits ----
        float lg[32];
#pragma unroll
        for (int j = 0; j < 32; ++j) {
            const float4* kr = (const float4*)(KV + j * 64);
            float dot = 0.f;
#pragma unroll
            for (int i = 0; i < 16; ++i) {
                float4 kv4 = kr[i];
                dot += qr[i].x * kv4.x + qr[i].y * kv4.y +
                       qr[i].z * kv4.z + qr[i].w * kv4.w;
            }
            int kpos = kbase + j;
            bool valid = glob ? true
                              : ((kpos >= NGLB) && (kpos < S_LEN) &&
                                 (kpos - s <= WINSZ) && (s - kpos <= WINSZ));
            float lv = NEGV;
            if (valid) lv = dot + amb[kpos];
            lg[j] = lv;
        }

        float tmax = lg[0];
#pragma unroll
        for (int j = 1; j < 32; ++j) tmax = fmaxf(tmax, lg[j]);
        float mnew = fmaxf(mrun, tmax);
        float corr = __expf(mrun - mnew);
        lrun *= corr;
#pragma unroll
        for (int i = 0; i < 16; ++i) {
            o[i].x *= corr; o[i].y *= corr; o[i].z *= corr; o[i].w *= corr;
        }

        // ---- stage V tile ----
        __syncthreads();
#pragma unroll
        for (int l2 = 0; l2 < 16; ++l2) {
            int e = l2 * 128 + t;
            int j = e >> 6, d = e & 63;
            int kpos = kbase + j;
            float val = 0.f;
            if ((unsigned)kpos < (unsigned)S_LEN) val = vh[(long)kpos * DH + d];
            KV[e] = val;
        }
        __syncthreads();

        // ---- accumulate ----
#pragma unroll
        for (int j = 0; j < 32; ++j) {
            float p = __expf(lg[j] - mnew);
            lrun += p;
            const float4* vr = (const float4*)(KV + j * 64);
#pragma unroll
            for (int i = 0; i < 16; ++i) {
                float4 vv = vr[i];
                o[i].x += p * vv.x; o[i].y += p * vv.y;
                o[i].z += p * vv.z; o[i].w += p * vv.w;
            }
        }
        mrun = mnew;
    }

    const float inv = 1.f / lrun;
    float4* outp = (float4*)(ctx + ((long)(b * S_LEN + s)) * D_MODEL + h * DH);
#pragma unroll
    for (int i = 0; i < 16; ++i)
        outp[i] = make_float4(o[i].x * inv, o[i].y * inv, o[i].z * inv, o[i].w * inv);
}

// ---------------------------------------------------------------------------
// Global-query attention: rows s in [0, NG) attend to all S keys.
// One wave (64 threads) per (b, h, g).
// ---------------------------------------------------------------------------
__global__ __launch_bounds__(64) void glob_attn_k(
    const float* __restrict__ q, const float* __restrict__ k,
    const float* __restrict__ v, const float* __restrict__ am,
    float* __restrict__ ctx)
{
    __shared__ float ls[S_LEN];  // 16 KB
    const int blk = blockIdx.x;            // B*NH*NG = 768
    const int g = blk & 31;
    const int h = (blk >> 5) % NHEAD;
    const int b = blk / (32 * NHEAD);
    const int t = threadIdx.x;             // 0..63

    const float* kh  = k + ((long)b * NHEAD + h) * S_LEN * DH;
    const float* vh  = v + ((long)b * NHEAD + h) * S_LEN * DH;
    const float* amb = am + (long)b * S_LEN;

    float4 qr[16];
    {
        const float4* q4 = (const float4*)(q + (((long)b * NHEAD + h) * S_LEN + g) * DH);
#pragma unroll
        for (int i = 0; i < 16; ++i) qr[i] = q4[i];
    }

    float lmax = -1e30f;
    for (int jj = 0; jj < 64; ++jj) {
        int j = jj * 64 + t;
        const float4* kr = (const float4*)(kh + (long)j * DH);
        float dot = 0.f;
#pragma unroll
        for (int i = 0; i < 16; ++i) {
            float4 kv4 = kr[i];
            dot += qr[i].x * kv4.x + qr[i].y * kv4.y +
                   qr[i].z * kv4.z + qr[i].w * kv4.w;
        }
        float lv = dot + amb[j];
        ls[j] = lv;
        lmax = fmaxf(lmax, lv);
    }
#pragma unroll
    for (int off = 32; off; off >>= 1) lmax = fmaxf(lmax, __shfl_xor(lmax, off));
    __syncthreads();

    float lsum = 0.f;
    for (int jj = 0; jj < 64; ++jj) {
        int j = jj * 64 + t;
        float p = __expf(ls[j] - lmax);
        ls[j] = p;
        lsum += p;
    }
#pragma unroll
    for (int off = 32; off; off >>= 1) lsum += __shfl_xor(lsum, off);
    __syncthreads();

    // thread t owns output dim d = t
    float acc = 0.f;
    for (int j = 0; j < S_LEN; ++j) acc += ls[j] * vh[(long)j * DH + t];

    ctx[((long)(b * S_LEN + g)) * D_MODEL + h * DH + t] = acc / lsum;
}

// ---------------------------------------------------------------------------
// LayerNorm over rows of 768. One block (256 threads) per row. Safe in-place.
// ---------------------------------------------------------------------------
__global__ __launch_bounds__(256) void ln_k(
    const float* __restrict__ in, float* __restrict__ out,
    const float* __restrict__ gw, const float* __restrict__ bw)
{
    __shared__ float red[256];
    const long row = blockIdx.x;
    const float* x = in + row * D_MODEL;
    const int t = threadIdx.x;
    float v0 = x[t], v1 = x[t + 256], v2 = x[t + 512];

    red[t] = v0 + v1 + v2;
    __syncthreads();
    for (int off = 128; off; off >>= 1) {
        if (t < off) red[t] += red[t + off];
        __syncthreads();
    }
    const float mu = red[0] * (1.f / 768.f);
    __syncthreads();

    float d0 = v0 - mu, d1 = v1 - mu, d2 = v2 - mu;
    red[t] = d0 * d0 + d1 * d1 + d2 * d2;
    __syncthreads();
    for (int off = 128; off; off >>= 1) {
        if (t < off) red[t] += red[t + off];
        __syncthreads();
    }
    const float var = red[0] * (1.f / 768.f);
    const float rs = rsqrtf(var + 1e-12f);

    float* y = out + row * D_MODEL;
    y[t]       = d0 * rs * gw[t]       + bw[t];
    y[t + 256] = d1 * rs * gw[t + 256] + bw[t + 256];
    y[t + 512] = d2 * rs * gw[t + 512] + bw[t + 512];
}

// ---------------------------------------------------------------------------
extern "C" void kernel_launch(void* const* d_in, const int* in_sizes, int n_in,
                              void* d_out, int out_size, void* d_ws, size_t ws_size,
                              hipStream_t stream)
{
    const float* hid  = (const float*)d_in[0];
    const float* am   = (const float*)d_in[1];
    const float* Wq   = (const float*)d_in[2];
    const float* bq   = (const float*)d_in[3];
    const float* Wk   = (const float*)d_in[4];
    const float* bk   = (const float*)d_in[5];
    const float* Wv   = (const float*)d_in[6];
    const float* bv   = (const float*)d_in[7];
    const float* Wo   = (const float*)d_in[8];
    const float* bo   = (const float*)d_in[9];
    const float* ln1g = (const float*)d_in[10];
    const float* ln1b = (const float*)d_in[11];
    const float* Wi   = (const float*)d_in[12];
    const float* bi   = (const float*)d_in[13];
    const float* Wo2  = (const float*)d_in[14];
    const float* bo2  = (const float*)d_in[15];
    const float* ln2g = (const float*)d_in[16];
    const float* ln2b = (const float*)d_in[17];

    const long M = (long)B_SZ * S_LEN;         // 8192
    const long NQ = (long)B_SZ * NHEAD * S_LEN * DH;  // 6291456

    float* ws   = (float*)d_ws;
    float* qb   = ws;                 // 6291456
    float* kb   = qb + NQ;            // 6291456
    float* vb   = kb + NQ;            // 6291456
    float* ctx  = vb + NQ;            // 6291456
    // inter (8192x3072 = 25165824 floats) aliases [qb .. ctx] which are dead
    // by the time it is written (stream-ordered).
    float* inter = ws;
    float* tmp  = ws + 25165824;      // attn residual / attn_out (in-place LN)
    float* tmp2 = tmp + NQ;           // FFN residual
    (void)ws_size; (void)in_sizes; (void)n_in; (void)out_size;

    dim3 blk(256);
    dim3 g768(D_MODEL / 128, M / 128);    // (6, 64)
    dim3 g3072(FF_DIM / 128, M / 128);    // (24, 64)

    // QKV projections (q scaled by 1/sqrt(Dh))
    gemm_k<2><<<g768, blk, 0, stream>>>(hid, Wq, bq, nullptr, qb, M, D_MODEL, D_MODEL, 0.125f);
    gemm_k<2><<<g768, blk, 0, stream>>>(hid, Wk, bk, nullptr, kb, M, D_MODEL, D_MODEL, 1.f);
    gemm_k<2><<<g768, blk, 0, stream>>>(hid, Wv, bv, nullptr, vb, M, D_MODEL, D_MODEL, 1.f);

    // attention
    band_attn_k<<<dim3(B_SZ * NHEAD * 32), dim3(128), 0, stream>>>(qb, kb, vb, am, ctx);
    glob_attn_k<<<dim3(B_SZ * NHEAD * NGLB), dim3(64), 0, stream>>>(qb, kb, vb, am, ctx);

    // attn_out = LN(ctx @ Wo + bo + hid)
    gemm_k<0><<<g768, blk, 0, stream>>>(ctx, Wo, bo, hid, tmp, M, D_MODEL, D_MODEL, 1.f);
    ln_k<<<dim3(M), blk, 0, stream>>>(tmp, tmp, ln1g, ln1b);

    // inter = gelu(attn_out @ Wi + bi)
    gemm_k<1><<<g3072, blk, 0, stream>>>(tmp, Wi, bi, nullptr, inter, M, FF_DIM, D_MODEL, 1.f);

    // out = LN(inter @ Wo2 + bo2 + attn_out)
    gemm_k<0><<<g768, blk, 0, stream>>>(inter, Wo2, bo2, tmp, tmp2, M, D_MODEL, FF_DIM, 1.f);
    ln_k<<<dim3(M), blk, 0, stream>>>(tmp2, (float*)d_out, ln2g, ln2b);
}

// Round 2
// 1199.829 us; speedup vs baseline: 2.2342x; 2.2342x over previous
//
#include <hip/hip_runtime.h>
#include <math.h>

#define NHEAD 12
#define DH 64
#define S_LEN 4096
#define B_SZ 2
#define D_MODEL 768
#define FF_DIM 3072
#define WINSZ 128
#define NGLB 32
#define NEGV -1e9f

typedef __attribute__((ext_vector_type(8))) short bf16x8;
typedef __attribute__((ext_vector_type(4))) float floatx4;

__device__ __forceinline__ unsigned short f2bf(float x) {
    union { float f; unsigned u; } v; v.f = x;
    unsigned r = v.u + 0x7fffu + ((v.u >> 16) & 1u);
    return (unsigned short)(r >> 16);
}

__device__ __forceinline__ void async_copy16(const unsigned short* g, unsigned short* l) {
    __builtin_amdgcn_global_load_lds(
        (const __attribute__((address_space(1))) void*)g,
        (__attribute__((address_space(3))) void*)l, 16, 0, 0);
}

// ---------------------------------------------------------------------------
// fp32 -> bf16 elementwise (row-major copy). n must be divisible by 4.
// ---------------------------------------------------------------------------
__global__ __launch_bounds__(256) void conv_k(
    const float* __restrict__ x, unsigned short* __restrict__ y, long n)
{
    long i = ((long)blockIdx.x * 256 + threadIdx.x) * 4;
    if (i >= n) return;
    float4 v = *(const float4*)(x + i);
    ushort4 o;
    o.x = f2bf(v.x); o.y = f2bf(v.y); o.z = f2bf(v.z); o.w = f2bf(v.w);
    *(ushort4*)(y + i) = o;
}

// ---------------------------------------------------------------------------
// W (KxN fp32, row-major) -> WT (NxK bf16). K, N multiples of 32.
// block (32,8), grid (N/32, K/32)
// ---------------------------------------------------------------------------
__global__ __launch_bounds__(256) void transpose_k(
    const float* __restrict__ W, unsigned short* __restrict__ WT, int K, int N)
{
    __shared__ float tile[32][33];
    const int tx = threadIdx.x, ty = threadIdx.y;
    const int n0 = blockIdx.x * 32, k0 = blockIdx.y * 32;
#pragma unroll
    for (int i = 0; i < 4; ++i)
        tile[ty + 8 * i][tx] = W[(long)(k0 + ty + 8 * i) * N + n0 + tx];
    __syncthreads();
#pragma unroll
    for (int i = 0; i < 4; ++i)
        WT[(long)(n0 + ty + 8 * i) * K + k0 + tx] = f2bf(tile[tx][ty + 8 * i]);
}

// ---------------------------------------------------------------------------
// bf16 MFMA GEMM: C = epi(A @ BT^T + bias)
// A: MxK bf16 row-major; BT: NxK bf16 row-major (i.e. W transposed).
// 128x128 tile, BK=32, 256 threads = 4 waves (2x2), each wave 64x64 = 4x4
// mfma_f32_16x16x32_bf16 tiles. global_load_lds width 16 staging.
// EPI 0: +bias +resid(fp32) -> fp32
// EPI 1: gelu(exact) -> bf16
// EPI 2: *scale, scatter fp32 to (B,NH,S,DH)
// ---------------------------------------------------------------------------
template <int EPI>
__global__ __launch_bounds__(256) void gemm_bf(
    const unsigned short* __restrict__ A, const unsigned short* __restrict__ BT,
    const float* __restrict__ bias, const float* __restrict__ resid,
    void* __restrict__ out, int M, int N, int K, float scale)
{
    __shared__ unsigned short As[128 * 32];
    __shared__ unsigned short Bs[128 * 32];
    const int tid = threadIdx.x;
    const int wave = tid >> 6, lane = tid & 63;
    const int m0 = blockIdx.y * 128, n0 = blockIdx.x * 128;
    const int wr = (wave >> 1) * 64, wc = (wave & 1) * 64;

    floatx4 acc[4][4];
#pragma unroll
    for (int i = 0; i < 4; ++i)
#pragma unroll
        for (int j = 0; j < 4; ++j) acc[i][j] = (floatx4){0.f, 0.f, 0.f, 0.f};

    const int srow = lane >> 2;          // 0..15 row within segment
    const int schk = (lane & 3) * 8;     // bf16 offset of 16B chunk
    const int r = lane & 15;
    const int q8 = (lane >> 4) * 8;

    for (int k0 = 0; k0 < K; k0 += 32) {
#pragma unroll
        for (int gi = 0; gi < 2; ++gi) {
            const int g = wave * 2 + gi;
            const unsigned short* ga =
                A + (long)(m0 + g * 16 + srow) * K + k0 + schk;
            async_copy16(ga, &As[g * 512]);
            const unsigned short* gb =
                BT + (long)(n0 + g * 16 + srow) * K + k0 + schk;
            async_copy16(gb, &Bs[g * 512]);
        }
        __syncthreads();

        bf16x8 af[4], bfr[4];
#pragma unroll
        for (int i = 0; i < 4; ++i) {
            af[i]  = *(const bf16x8*)&As[(wr + i * 16 + r) * 32 + q8];
            bfr[i] = *(const bf16x8*)&Bs[(wc + i * 16 + r) * 32 + q8];
        }
#pragma unroll
        for (int i = 0; i < 4; ++i)
#pragma unroll
            for (int j = 0; j < 4; ++j)
                acc[i][j] = __builtin_amdgcn_mfma_f32_16x16x32_bf16(
                    af[i], bfr[j], acc[i][j], 0, 0, 0);
        __syncthreads();
    }

    // C/D layout: col = lane&15, row = (lane>>4)*4 + reg
    const int col_l = lane & 15, row_l = (lane >> 4) * 4;
#pragma unroll
    for (int i = 0; i < 4; ++i) {
#pragma unroll
        for (int j = 0; j < 4; ++j) {
            const int n = n0 + wc + j * 16 + col_l;
            const float bv = bias[n];
#pragma unroll
            for (int rg = 0; rg < 4; ++rg) {
                const int m = m0 + wr + i * 16 + row_l + rg;
                float v = acc[i][j][rg] + bv;
                if (EPI == 0) {
                    ((float*)out)[(long)m * N + n] = v + resid[(long)m * N + n];
                } else if (EPI == 1) {
                    v = 0.5f * v * (1.f + erff(v * 0.70710678118654752f));
                    ((unsigned short*)out)[(long)m * N + n] = f2bf(v);
                } else {
                    const int bb = m >> 12, s = m & 4095;
                    const int hh = n >> 6, dh = n & 63;
                    ((float*)out)[(((long)bb * NHEAD + hh) * S_LEN + s) * DH + dh] =
                        v * scale;
                }
            }
        }
    }
}

// ---------------------------------------------------------------------------
// Band (sliding-window) attention + global-key columns. fp32 compute,
// bf16 ctx output (ctx feeds the Wo MFMA GEMM).
// ---------------------------------------------------------------------------
__global__ __launch_bounds__(128) void band_attn_k(
    const float* __restrict__ q, const float* __restrict__ k,
    const float* __restrict__ v, const float* __restrict__ am,
    unsigned short* __restrict__ ctx)
{
    __shared__ float KV[32 * 64];
    const int blk = blockIdx.x;            // B*NH*C = 768
    const int c = blk & 31;
    const int h = (blk >> 5) % NHEAD;
    const int b = blk / (32 * NHEAD);
    const int t = threadIdx.x;
    const int s = c * WINSZ + t;

    const float* kh  = k + ((long)b * NHEAD + h) * S_LEN * DH;
    const float* vh  = v + ((long)b * NHEAD + h) * S_LEN * DH;
    const float* amb = am + (long)b * S_LEN;

    float4 qr[16];
    {
        const float4* q4 = (const float4*)(q + (((long)b * NHEAD + h) * S_LEN + s) * DH);
#pragma unroll
        for (int i = 0; i < 16; ++i) qr[i] = q4[i];
    }

    float mrun = -1e30f, lrun = 0.f;
    float4 o[16];
#pragma unroll
    for (int i = 0; i < 16; ++i) o[i] = make_float4(0.f, 0.f, 0.f, 0.f);

    for (int tile = 0; tile < 13; ++tile) {
        const bool glob = (tile == 12);
        const int kbase = glob ? 0 : (c * WINSZ - WINSZ + tile * 32);

        __syncthreads();
#pragma unroll
        for (int l2 = 0; l2 < 16; ++l2) {
            int e = l2 * 128 + t;
            int j = e >> 6, d = e & 63;
            int kpos = kbase + j;
            float val = 0.f;
            if ((unsigned)kpos < (unsigned)S_LEN) val = kh[(long)kpos * DH + d];
            KV[e] = val;
        }
        __syncthreads();

        float lg[32];
#pragma unroll
        for (int j = 0; j < 32; ++j) {
            const float4* kr = (const float4*)(KV + j * 64);
            float dot = 0.f;
#pragma unroll
            for (int i = 0; i < 16; ++i) {
                float4 kv4 = kr[i];
                dot += qr[i].x * kv4.x + qr[i].y * kv4.y +
                       qr[i].z * kv4.z + qr[i].w * kv4.w;
            }
            int kpos = kbase + j;
            bool valid = glob ? true
                              : ((kpos >= NGLB) && (kpos < S_LEN) &&
                                 (kpos - s <= WINSZ) && (s - kpos <= WINSZ));
            float lv = NEGV;
            if (valid) lv = dot + amb[kpos];
            lg[j] = lv;
        }

        float tmax = lg[0];
#pragma unroll
        for (int j = 1; j < 32; ++j) tmax = fmaxf(tmax, lg[j]);
        float mnew = fmaxf(mrun, tmax);
        float corr = __expf(mrun - mnew);
        lrun *= corr;
#pragma unroll
        for (int i = 0; i < 16; ++i) {
            o[i].x *= corr; o[i].y *= corr; o[i].z *= corr; o[i].w *= corr;
        }

        __syncthreads();
#pragma unroll
        for (int l2 = 0; l2 < 16; ++l2) {
            int e = l2 * 128 + t;
            int j = e >> 6, d = e & 63;
            int kpos = kbase + j;
            float val = 0.f;
            if ((unsigned)kpos < (unsigned)S_LEN) val = vh[(long)kpos * DH + d];
            KV[e] = val;
        }
        __syncthreads();

#pragma unroll
        for (int j = 0; j < 32; ++j) {
            float p = __expf(lg[j] - mnew);
            lrun += p;
            const float4* vr = (const float4*)(KV + j * 64);
#pragma unroll
            for (int i = 0; i < 16; ++i) {
                float4 vv = vr[i];
                o[i].x += p * vv.x; o[i].y += p * vv.y;
                o[i].z += p * vv.z; o[i].w += p * vv.w;
            }
        }
        mrun = mnew;
    }

    const float inv = 1.f / lrun;
    ushort4* outp = (ushort4*)(ctx + ((long)(b * S_LEN + s)) * D_MODEL + h * DH);
#pragma unroll
    for (int i = 0; i < 16; ++i) {
        ushort4 ov;
        ov.x = f2bf(o[i].x * inv); ov.y = f2bf(o[i].y * inv);
        ov.z = f2bf(o[i].z * inv); ov.w = f2bf(o[i].w * inv);
        outp[i] = ov;
    }
}

// ---------------------------------------------------------------------------
// Global-query attention: rows s in [0, NG) attend to all S keys.
// One wave per (b, h, g). Overwrites band rows (stream-ordered).
// ---------------------------------------------------------------------------
__global__ __launch_bounds__(64) void glob_attn_k(
    const float* __restrict__ q, const float* __restrict__ k,
    const float* __restrict__ v, const float* __restrict__ am,
    unsigned short* __restrict__ ctx)
{
    __shared__ float ls[S_LEN];
    const int blk = blockIdx.x;            // B*NH*NG = 768
    const int g = blk & 31;
    const int h = (blk >> 5) % NHEAD;
    const int b = blk / (32 * NHEAD);
    const int t = threadIdx.x;

    const float* kh  = k + ((long)b * NHEAD + h) * S_LEN * DH;
    const float* vh  = v + ((long)b * NHEAD + h) * S_LEN * DH;
    const float* amb = am + (long)b * S_LEN;

    float4 qr[16];
    {
        const float4* q4 = (const float4*)(q + (((long)b * NHEAD + h) * S_LEN + g) * DH);
#pragma unroll
        for (int i = 0; i < 16; ++i) qr[i] = q4[i];
    }

    float lmax = -1e30f;
    for (int jj = 0; jj < 64; ++jj) {
        int j = jj * 64 + t;
        const float4* kr = (const float4*)(kh + (long)j * DH);
        float dot = 0.f;
#pragma unroll
        for (int i = 0; i < 16; ++i) {
            float4 kv4 = kr[i];
            dot += qr[i].x * kv4.x + qr[i].y * kv4.y +
                   qr[i].z * kv4.z + qr[i].w * kv4.w;
        }
        float lv = dot + amb[j];
        ls[j] = lv;
        lmax = fmaxf(lmax, lv);
    }
#pragma unroll
    for (int off = 32; off; off >>= 1) lmax = fmaxf(lmax, __shfl_xor(lmax, off));
    __syncthreads();

    float lsum = 0.f;
    for (int jj = 0; jj < 64; ++jj) {
        int j = jj * 64 + t;
        float p = __expf(ls[j] - lmax);
        ls[j] = p;
        lsum += p;
    }
#pragma unroll
    for (int off = 32; off; off >>= 1) lsum += __shfl_xor(lsum, off);
    __syncthreads();

    float acc = 0.f;
    for (int j = 0; j < S_LEN; ++j) acc += ls[j] * vh[(long)j * DH + t];

    ctx[((long)(b * S_LEN + g)) * D_MODEL + h * DH + t] = f2bf(acc / lsum);
}

// ---------------------------------------------------------------------------
// LayerNorm over rows of 768. Optionally also emits a bf16 copy.
// ---------------------------------------------------------------------------
__global__ __launch_bounds__(256) void ln_k(
    const float* __restrict__ in, float* __restrict__ out,
    unsigned short* __restrict__ out_bf,
    const float* __restrict__ gw, const float* __restrict__ bw)
{
    __shared__ float red[256];
    const long row = blockIdx.x;
    const float* x = in + row * D_MODEL;
    const int t = threadIdx.x;
    float v0 = x[t], v1 = x[t + 256], v2 = x[t + 512];

    red[t] = v0 + v1 + v2;
    __syncthreads();
    for (int off = 128; off; off >>= 1) {
        if (t < off) red[t] += red[t + off];
        __syncthreads();
    }
    const float mu = red[0] * (1.f / 768.f);
    __syncthreads();

    float d0 = v0 - mu, d1 = v1 - mu, d2 = v2 - mu;
    red[t] = d0 * d0 + d1 * d1 + d2 * d2;
    __syncthreads();
    for (int off = 128; off; off >>= 1) {
        if (t < off) red[t] += red[t + off];
        __syncthreads();
    }
    const float var = red[0] * (1.f / 768.f);
    const float rs = rsqrtf(var + 1e-12f);

    const float y0 = d0 * rs * gw[t] + bw[t];
    const float y1 = d1 * rs * gw[t + 256] + bw[t + 256];
    const float y2 = d2 * rs * gw[t + 512] + bw[t + 512];
    float* y = out + row * D_MODEL;
    y[t] = y0; y[t + 256] = y1; y[t + 512] = y2;
    if (out_bf) {
        unsigned short* yb = out_bf + row * D_MODEL;
        yb[t] = f2bf(y0); yb[t + 256] = f2bf(y1); yb[t + 512] = f2bf(y2);
    }
}

// ---------------------------------------------------------------------------
extern "C" void kernel_launch(void* const* d_in, const int* in_sizes, int n_in,
                              void* d_out, int out_size, void* d_ws, size_t ws_size,
                              hipStream_t stream)
{
    const float* hid  = (const float*)d_in[0];
    const float* am   = (const float*)d_in[1];
    const float* Wq   = (const float*)d_in[2];
    const float* bq   = (const float*)d_in[3];
    const float* Wk   = (const float*)d_in[4];
    const float* bk   = (const float*)d_in[5];
    const float* Wv   = (const float*)d_in[6];
    const float* bv   = (const float*)d_in[7];
    const float* Wo   = (const float*)d_in[8];
    const float* bo   = (const float*)d_in[9];
    const float* ln1g = (const float*)d_in[10];
    const float* ln1b = (const float*)d_in[11];
    const float* Wi   = (const float*)d_in[12];
    const float* bi   = (const float*)d_in[13];
    const float* Wo2  = (const float*)d_in[14];
    const float* bo2  = (const float*)d_in[15];
    const float* ln2g = (const float*)d_in[16];
    const float* ln2b = (const float*)d_in[17];

    const long M  = (long)B_SZ * S_LEN;                 // 8192
    const long NQ = (long)B_SZ * NHEAD * S_LEN * DH;    // 6291456

    float* ws = (float*)d_ws;
    // fp32 buffers
    float* qb  = ws;               // [0, NQ)
    float* kb  = ws + NQ;          // [NQ, 2NQ)
    float* vb  = ws + 2 * NQ;      // [2NQ, 3NQ)
    unsigned short* ctxb = (unsigned short*)(ws + 3 * NQ);        // NQ bf16
    unsigned short* hidb = (unsigned short*)(ws + 3 * NQ + NQ/2); // NQ bf16
    unsigned short* wqt  = (unsigned short*)(ws + 4 * NQ);
    unsigned short* wkt  = wqt + 589824;
    unsigned short* wvt  = wkt + 589824;
    unsigned short* wot  = wvt + 589824;
    unsigned short* wit  = wot + 589824;    // 2359296 bf16
    unsigned short* wo2t = wit + 2359296;   // 2359296 bf16
    float* tmp = ws + 28704768;             // attn_out fp32 (in-place LN1)
    // aliases over dead regions:
    unsigned short* interb = (unsigned short*)ws;            // over q,k (dead)
    unsigned short* attnb  = (unsigned short*)(ws + 2 * NQ); // over v (dead)
    float* tmp2 = ws + 3 * NQ;                               // over ctxb/hidb (dead)
    (void)ws_size; (void)in_sizes; (void)n_in; (void)out_size;

    // weight transposes + activations convert
    transpose_k<<<dim3(24, 24), dim3(32, 8), 0, stream>>>(Wq, wqt, 768, 768);
    transpose_k<<<dim3(24, 24), dim3(32, 8), 0, stream>>>(Wk, wkt, 768, 768);
    transpose_k<<<dim3(24, 24), dim3(32, 8), 0, stream>>>(Wv, wvt, 768, 768);
    transpose_k<<<dim3(24, 24), dim3(32, 8), 0, stream>>>(Wo, wot, 768, 768);
    transpose_k<<<dim3(96, 24), dim3(32, 8), 0, stream>>>(Wi, wit, 768, 3072);
    transpose_k<<<dim3(24, 96), dim3(32, 8), 0, stream>>>(Wo2, wo2t, 3072, 768);
    conv_k<<<dim3((NQ / 4 + 255) / 256), dim3(256), 0, stream>>>(hid, hidb, NQ);

    dim3 blk(256);
    dim3 g768(6, 64), g3072(24, 64);

    // QKV projections (q scaled by 1/sqrt(Dh))
    gemm_bf<2><<<g768, blk, 0, stream>>>(hidb, wqt, bq, nullptr, qb, M, 768, 768, 0.125f);
    gemm_bf<2><<<g768, blk, 0, stream>>>(hidb, wkt, bk, nullptr, kb, M, 768, 768, 1.f);
    gemm_bf<2><<<g768, blk, 0, stream>>>(hidb, wvt, bv, nullptr, vb, M, 768, 768, 1.f);

    // attention -> ctx (bf16)
    band_attn_k<<<dim3(768), dim3(128), 0, stream>>>(qb, kb, vb, am, ctxb);
    glob_attn_k<<<dim3(768), dim3(64), 0, stream>>>(qb, kb, vb, am, ctxb);

    // attn_out = LN(ctx @ Wo + bo + hid) ; fp32 + bf16 copy
    gemm_bf<0><<<g768, blk, 0, stream>>>(ctxb, wot, bo, hid, tmp, M, 768, 768, 1.f);
    ln_k<<<dim3(M), blk, 0, stream>>>(tmp, tmp, attnb, ln1g, ln1b);

    // inter = gelu(attn_out @ Wi + bi) -> bf16
    gemm_bf<1><<<g3072, blk, 0, stream>>>(attnb, wit, bi, nullptr, interb, M, 3072, 768, 1.f);

    // out = LN(inter @ Wo2 + bo2 + attn_out)
    gemm_bf<0><<<g768, blk, 0, stream>>>(interb, wo2t, bo2, tmp, tmp2, M, 768, 3072, 1.f);
    ln_k<<<dim3(M), blk, 0, stream>>>(tmp2, (float*)d_out, nullptr, ln2g, ln2b);
}

// Round 4
// 628.050 us; speedup vs baseline: 4.2682x; 1.9104x over previous
//
#include <hip/hip_runtime.h>
#include <math.h>

#define NHEAD 12
#define DH 64
#define S_LEN 4096
#define B_SZ 2
#define D_MODEL 768
#define FF_DIM 3072
#define WINSZ 128
#define NGLB 32
#define NEGV -1e9f

typedef __attribute__((ext_vector_type(8))) short bf16x8;
typedef __attribute__((ext_vector_type(4))) float floatx4;

__device__ __forceinline__ unsigned short f2bf(float x) {
    union { float f; unsigned u; } v; v.f = x;
    unsigned r = v.u + 0x7fffu + ((v.u >> 16) & 1u);
    return (unsigned short)(r >> 16);
}
__device__ __forceinline__ float bf2f(unsigned short x) {
    union { unsigned u; float f; } v; v.u = ((unsigned)x) << 16;
    return v.f;
}

__device__ __forceinline__ void async_copy16(const unsigned short* g, unsigned short* l) {
    __builtin_amdgcn_global_load_lds(
        (const __attribute__((address_space(1))) void*)g,
        (__attribute__((address_space(3))) void*)l, 16, 0, 0);
}

// ---------------------------------------------------------------------------
// fp32 -> bf16 elementwise
// ---------------------------------------------------------------------------
__global__ __launch_bounds__(256) void conv_k(
    const float* __restrict__ x, unsigned short* __restrict__ y, long n)
{
    long i = ((long)blockIdx.x * 256 + threadIdx.x) * 4;
    if (i >= n) return;
    float4 v = *(const float4*)(x + i);
    ushort4 o;
    o.x = f2bf(v.x); o.y = f2bf(v.y); o.z = f2bf(v.z); o.w = f2bf(v.w);
    *(ushort4*)(y + i) = o;
}

// ---------------------------------------------------------------------------
// W (KxN fp32) -> WT (NxK bf16)
// ---------------------------------------------------------------------------
__global__ __launch_bounds__(256) void transpose_k(
    const float* __restrict__ W, unsigned short* __restrict__ WT, int K, int N)
{
    __shared__ float tile[32][33];
    const int tx = threadIdx.x, ty = threadIdx.y;
    const int n0 = blockIdx.x * 32, k0 = blockIdx.y * 32;
#pragma unroll
    for (int i = 0; i < 4; ++i)
        tile[ty + 8 * i][tx] = W[(long)(k0 + ty + 8 * i) * N + n0 + tx];
    __syncthreads();
#pragma unroll
    for (int i = 0; i < 4; ++i)
        WT[(long)(n0 + ty + 8 * i) * K + k0 + tx] = f2bf(tile[tx][ty + 8 * i]);
}

// ---------------------------------------------------------------------------
// V (B,NH,S,DH) bf16 -> Vt (B,NH,DH,S) bf16
// grid (S/32, B*NH), 256 threads: wave w handles keys s0+w*8..+7, lane = dim.
// ---------------------------------------------------------------------------
__global__ __launch_bounds__(256) void vt_k(
    const unsigned short* __restrict__ v, unsigned short* __restrict__ vt)
{
    const int bh = blockIdx.y;
    const int s0 = blockIdx.x * 32;
    const int w = threadIdx.x >> 6, lane = threadIdx.x & 63;
    const unsigned short* src = v + ((long)bh * S_LEN + s0 + w * 8) * DH + lane;
    unsigned short r[8];
#pragma unroll
    for (int j = 0; j < 8; ++j) r[j] = src[j * DH];
    unsigned short* dst = vt + ((long)bh * DH + lane) * S_LEN + s0 + w * 8;
    ushort4 lo, hi;
    lo.x = r[0]; lo.y = r[1]; lo.z = r[2]; lo.w = r[3];
    hi.x = r[4]; hi.y = r[5]; hi.z = r[6]; hi.w = r[7];
    *(ushort4*)dst = lo;
    *(ushort4*)(dst + 4) = hi;
}

// ---------------------------------------------------------------------------
// bf16 MFMA GEMM (m97-style): C = epi(A @ BT^T + bias)
// EPI 0: +bias +resid(fp32) -> fp32
// EPI 1: gelu -> bf16
// EPI 2: *scale -> bf16 scatter to (B,NH,S,DH)
// ---------------------------------------------------------------------------
template <int EPI>
__global__ __launch_bounds__(256) void gemm_bf(
    const unsigned short* __restrict__ A, const unsigned short* __restrict__ BT,
    const float* __restrict__ bias, const float* __restrict__ resid,
    void* __restrict__ out, int M, int N, int K, float scale)
{
    __shared__ unsigned short As[128 * 32];
    __shared__ unsigned short Bs[128 * 32];
    const int tid = threadIdx.x;
    const int wave = tid >> 6, lane = tid & 63;
    const int m0 = blockIdx.y * 128, n0 = blockIdx.x * 128;
    const int wr = (wave >> 1) * 64, wc = (wave & 1) * 64;

    floatx4 acc[4][4];
#pragma unroll
    for (int i = 0; i < 4; ++i)
#pragma unroll
        for (int j = 0; j < 4; ++j) acc[i][j] = (floatx4){0.f, 0.f, 0.f, 0.f};

    const int srow = lane >> 2;
    const int schk = (lane & 3) * 8;
    const int r = lane & 15;
    const int q8 = (lane >> 4) * 8;

    for (int k0 = 0; k0 < K; k0 += 32) {
#pragma unroll
        for (int gi = 0; gi < 2; ++gi) {
            const int g = wave * 2 + gi;
            async_copy16(A + (long)(m0 + g * 16 + srow) * K + k0 + schk, &As[g * 512]);
            async_copy16(BT + (long)(n0 + g * 16 + srow) * K + k0 + schk, &Bs[g * 512]);
        }
        __syncthreads();

        bf16x8 af[4], bfr[4];
#pragma unroll
        for (int i = 0; i < 4; ++i) {
            af[i]  = *(const bf16x8*)&As[(wr + i * 16 + r) * 32 + q8];
            bfr[i] = *(const bf16x8*)&Bs[(wc + i * 16 + r) * 32 + q8];
        }
#pragma unroll
        for (int i = 0; i < 4; ++i)
#pragma unroll
            for (int j = 0; j < 4; ++j)
                acc[i][j] = __builtin_amdgcn_mfma_f32_16x16x32_bf16(
                    af[i], bfr[j], acc[i][j], 0, 0, 0);
        __syncthreads();
    }

    const int col_l = lane & 15, row_l = (lane >> 4) * 4;
#pragma unroll
    for (int i = 0; i < 4; ++i) {
#pragma unroll
        for (int j = 0; j < 4; ++j) {
            const int n = n0 + wc + j * 16 + col_l;
            const float bv = bias[n];
#pragma unroll
            for (int rg = 0; rg < 4; ++rg) {
                const int m = m0 + wr + i * 16 + row_l + rg;
                float v = acc[i][j][rg] + bv;
                if (EPI == 0) {
                    ((float*)out)[(long)m * N + n] = v + resid[(long)m * N + n];
                } else if (EPI == 1) {
                    v = 0.5f * v * (1.f + erff(v * 0.70710678118654752f));
                    ((unsigned short*)out)[(long)m * N + n] = f2bf(v);
                } else {
                    const int bb = m >> 12, s = m & 4095;
                    const int hh = n >> 6, dh = n & 63;
                    ((unsigned short*)out)[(((long)bb * NHEAD + hh) * S_LEN + s) * DH + dh] =
                        f2bf(v * scale);
                }
            }
        }
    }
}

// ---------------------------------------------------------------------------
// MFMA band attention. One block per (b,h,chunk); 4 waves x 32 queries.
// S^T = K·Q^T (m=key, n=query), online softmax per column, O^T += V^T·P^T.
// P^T relayout via per-wave LDS. 13 key tiles of 32 (12 band + 1 global).
// ---------------------------------------------------------------------------
__global__ __launch_bounds__(256) void band_mfma_k(
    const unsigned short* __restrict__ q, const unsigned short* __restrict__ k,
    const unsigned short* __restrict__ vt, const float* __restrict__ am,
    unsigned short* __restrict__ ctx)
{
    __shared__ unsigned short Ks[32 * 72];      // [key][dim], stride 72 u16
    __shared__ unsigned short Vs[64 * 40];      // [dim][key], stride 40 u16
    __shared__ unsigned short Ps[4][32 * 40];   // per wave [q][key], stride 40

    const int blk = blockIdx.x;
    const int c = blk & 31;
    const int h = (blk >> 5) % NHEAD;
    const int b = blk / (32 * NHEAD);
    const int tid = threadIdx.x;
    const int wave = tid >> 6, lane = tid & 63;
    const long bh = (long)b * NHEAD + h;

    const unsigned short* kh  = k + bh * S_LEN * DH;
    const unsigned short* vth = vt + bh * (long)DH * S_LEN;
    const float* amb = am + (long)b * S_LEN;

    const int q0 = c * WINSZ + wave * 32;
    const int ln15 = lane & 15, ln4 = lane >> 4;

    // Q B-fragments (loop-invariant): [nt][kstep]
    bf16x8 qf[2][2];
#pragma unroll
    for (int nt = 0; nt < 2; ++nt)
#pragma unroll
        for (int ks = 0; ks < 2; ++ks)
            qf[nt][ks] = *(const bf16x8*)(q + (bh * S_LEN + q0 + nt * 16 + ln15) * DH
                                          + ks * 32 + ln4 * 8);

    floatx4 o[4][2];
#pragma unroll
    for (int mt = 0; mt < 4; ++mt)
#pragma unroll
        for (int nt = 0; nt < 2; ++nt) o[mt][nt] = (floatx4){0.f, 0.f, 0.f, 0.f};
    float m_r[2] = {-1e30f, -1e30f}, l_r[2] = {0.f, 0.f};

    const int sk_key = tid >> 3, sk_ch = tid & 7;   // K staging: key, dim-chunk
    const int sv_dim = tid & 63, sv_ch = tid >> 6;  // V staging: dim, key-chunk
    const bf16x8 zero8 = {0, 0, 0, 0, 0, 0, 0, 0};

    for (int tile = 0; tile < 13; ++tile) {
        const bool glob = (tile == 12);
        const int kbase = glob ? 0 : (c * WINSZ - WINSZ + tile * 32);

        __syncthreads();
        {   // stage K tile [32 keys][64 dims]
            int kpos = kbase + sk_key;
            bf16x8 val = zero8;
            if ((unsigned)kpos < (unsigned)S_LEN)
                val = *(const bf16x8*)(kh + (long)kpos * DH + sk_ch * 8);
            *(bf16x8*)(&Ks[sk_key * 72 + sk_ch * 8]) = val;
        }
        {   // stage V^T tile [64 dims][32 keys]
            int kc = kbase + sv_ch * 8;
            bf16x8 val = zero8;
            if (kc >= 0 && kc + 8 <= S_LEN)
                val = *(const bf16x8*)(vth + (long)sv_dim * S_LEN + kc);
            *(bf16x8*)(&Vs[sv_dim * 40 + sv_ch * 8]) = val;
        }
        __syncthreads();

        // S^T = K · Q^T
        bf16x8 ak[2][2];
#pragma unroll
        for (int mt = 0; mt < 2; ++mt)
#pragma unroll
            for (int ks = 0; ks < 2; ++ks)
                ak[mt][ks] = *(const bf16x8*)(&Ks[(mt * 16 + ln15) * 72 + ks * 32 + ln4 * 8]);

        floatx4 s[2][2];
#pragma unroll
        for (int mt = 0; mt < 2; ++mt)
#pragma unroll
            for (int nt = 0; nt < 2; ++nt) {
                floatx4 acc = (floatx4){0.f, 0.f, 0.f, 0.f};
                acc = __builtin_amdgcn_mfma_f32_16x16x32_bf16(ak[mt][0], qf[nt][0], acc, 0, 0, 0);
                acc = __builtin_amdgcn_mfma_f32_16x16x32_bf16(ak[mt][1], qf[nt][1], acc, 0, 0, 0);
                s[mt][nt] = acc;
            }

        // mask + attention-mask add (C-layout: row=key=(lane>>4)*4+reg, col=q=lane&15)
#pragma unroll
        for (int mt = 0; mt < 2; ++mt) {
            const int kp0 = kbase + mt * 16 + ln4 * 4;
#pragma unroll
            for (int rg = 0; rg < 4; ++rg) {
                const int kpos = kp0 + rg;
                const bool kin = (unsigned)kpos < (unsigned)S_LEN;
                const float amv = kin ? amb[kpos] : 0.f;
#pragma unroll
                for (int nt = 0; nt < 2; ++nt) {
                    const int qpos = q0 + nt * 16 + ln15;
                    const int dlt = kpos > qpos ? kpos - qpos : qpos - kpos;
                    const bool valid = glob || (kpos >= NGLB && kin && dlt <= WINSZ);
                    s[mt][nt][rg] = valid ? s[mt][nt][rg] + amv : NEGV;
                }
            }
        }

        // online softmax update (per query column)
        float alpha[2];
#pragma unroll
        for (int nt = 0; nt < 2; ++nt) {
            float mx = s[0][nt][0];
#pragma unroll
            for (int rg = 1; rg < 4; ++rg) mx = fmaxf(mx, s[0][nt][rg]);
#pragma unroll
            for (int rg = 0; rg < 4; ++rg) mx = fmaxf(mx, s[1][nt][rg]);
            mx = fmaxf(mx, __shfl_xor(mx, 16));
            mx = fmaxf(mx, __shfl_xor(mx, 32));
            const float mn = fmaxf(m_r[nt], mx);
            alpha[nt] = __expf(m_r[nt] - mn);
            m_r[nt] = mn;
        }

        // P = exp(S - m): pack bf16 into per-wave LDS, accumulate l
#pragma unroll
        for (int nt = 0; nt < 2; ++nt) {
            float sum = 0.f;
#pragma unroll
            for (int mt = 0; mt < 2; ++mt) {
                ushort4 pk;
#pragma unroll
                for (int rg = 0; rg < 4; ++rg) {
                    const float p = __expf(s[mt][nt][rg] - m_r[nt]);
                    sum += p;
                    ((unsigned short*)&pk)[rg] = f2bf(p);
                }
                *(ushort4*)(&Ps[wave][(nt * 16 + ln15) * 40 + mt * 16 + ln4 * 4]) = pk;
            }
            sum += __shfl_xor(sum, 16);
            sum += __shfl_xor(sum, 32);
            l_r[nt] = l_r[nt] * alpha[nt] + sum;
        }

        // rescale O
#pragma unroll
        for (int mt = 0; mt < 4; ++mt)
#pragma unroll
            for (int nt = 0; nt < 2; ++nt)
#pragma unroll
                for (int rg = 0; rg < 4; ++rg) o[mt][nt][rg] *= alpha[nt];

        // O^T += V^T · P^T
        bf16x8 av[4], bp[2];
#pragma unroll
        for (int mt = 0; mt < 4; ++mt)
            av[mt] = *(const bf16x8*)(&Vs[(mt * 16 + ln15) * 40 + ln4 * 8]);
#pragma unroll
        for (int nt = 0; nt < 2; ++nt)
            bp[nt] = *(const bf16x8*)(&Ps[wave][(nt * 16 + ln15) * 40 + ln4 * 8]);
#pragma unroll
        for (int mt = 0; mt < 4; ++mt)
#pragma unroll
            for (int nt = 0; nt < 2; ++nt)
                o[mt][nt] = __builtin_amdgcn_mfma_f32_16x16x32_bf16(
                    av[mt], bp[nt], o[mt][nt], 0, 0, 0);
    }

    // epilogue: O^T C-layout row=dim, col=q
    const float inv0 = 1.f / l_r[0], inv1 = 1.f / l_r[1];
#pragma unroll
    for (int nt = 0; nt < 2; ++nt) {
        const float inv = nt ? inv1 : inv0;
        const long row = (long)b * S_LEN + q0 + nt * 16 + ln15;
#pragma unroll
        for (int mt = 0; mt < 4; ++mt) {
            ushort4 ov;
#pragma unroll
            for (int rg = 0; rg < 4; ++rg)
                ((unsigned short*)&ov)[rg] = f2bf(o[mt][nt][rg] * inv);
            *(ushort4*)(ctx + row * D_MODEL + h * DH + mt * 16 + ln4 * 4) = ov;
        }
    }
}

// ---------------------------------------------------------------------------
// Global-query attention: rows s<NG attend to all keys. One block (4 waves)
// per (b,h,g). Overwrites band rows (stream-ordered).
// ---------------------------------------------------------------------------
__global__ __launch_bounds__(256) void glob_attn_k(
    const unsigned short* __restrict__ q, const unsigned short* __restrict__ k,
    const unsigned short* __restrict__ v, const float* __restrict__ am,
    unsigned short* __restrict__ ctx)
{
    __shared__ float ls[S_LEN];
    __shared__ float red[256];
    __shared__ float qs[64];
    const int blk = blockIdx.x;
    const int g = blk & 31;
    const int h = (blk >> 5) % NHEAD;
    const int b = blk / (32 * NHEAD);
    const int t = threadIdx.x;
    const long bh = (long)b * NHEAD + h;
    const unsigned short* kh = k + bh * S_LEN * DH;
    const unsigned short* vh = v + bh * S_LEN * DH;
    const float* amb = am + (long)b * S_LEN;

    if (t < 8) {
        bf16x8 qv = *(const bf16x8*)(q + (bh * S_LEN + g) * DH + t * 8);
#pragma unroll
        for (int j = 0; j < 8; ++j) qs[t * 8 + j] = bf2f((unsigned short)qv[j]);
    }
    __syncthreads();

    float lmax = -1e30f;
#pragma unroll 2
    for (int i = 0; i < 16; ++i) {
        const int key = i * 256 + t;
        const unsigned short* kr = kh + (long)key * DH;
        float dot = 0.f;
#pragma unroll
        for (int ch = 0; ch < 8; ++ch) {
            bf16x8 kv = *(const bf16x8*)(kr + ch * 8);
#pragma unroll
            for (int j = 0; j < 8; ++j) dot += qs[ch * 8 + j] * bf2f((unsigned short)kv[j]);
        }
        const float lv = dot + amb[key];
        ls[key] = lv;
        lmax = fmaxf(lmax, lv);
    }
    red[t] = lmax; __syncthreads();
    for (int off = 128; off; off >>= 1) {
        if (t < off) red[t] = fmaxf(red[t], red[t + off]);
        __syncthreads();
    }
    const float bmax = red[0];
    __syncthreads();

    float lsum = 0.f;
#pragma unroll 2
    for (int i = 0; i < 16; ++i) {
        const int key = i * 256 + t;
        const float p = __expf(ls[key] - bmax);
        ls[key] = p;
        lsum += p;
    }
    red[t] = lsum; __syncthreads();
    for (int off = 128; off; off >>= 1) {
        if (t < off) red[t] += red[t + off];
        __syncthreads();
    }
    const float inv = 1.f / red[0];
    __syncthreads();

    // phase 2: wave w covers keys [w*1024, w*1024+1024), lane = dim
    const int w = t >> 6, lane = t & 63;
    float acc = 0.f;
#pragma unroll 4
    for (int j = 0; j < 1024; ++j) {
        const int key = w * 1024 + j;
        acc += ls[key] * bf2f(vh[(long)key * DH + lane]);
    }
    red[t] = acc; __syncthreads();
    if (t < 64) {
        const float ov = red[t] + red[t + 64] + red[t + 128] + red[t + 192];
        ctx[((long)b * S_LEN + g) * D_MODEL + h * DH + t] = f2bf(ov * inv);
    }
}

// ---------------------------------------------------------------------------
// LayerNorm rows of 768; optional bf16 copy.
// ---------------------------------------------------------------------------
__global__ __launch_bounds__(256) void ln_k(
    const float* __restrict__ in, float* __restrict__ out,
    unsigned short* __restrict__ out_bf,
    const float* __restrict__ gw, const float* __restrict__ bw)
{
    __shared__ float red[256];
    const long row = blockIdx.x;
    const float* x = in + row * D_MODEL;
    const int t = threadIdx.x;
    float v0 = x[t], v1 = x[t + 256], v2 = x[t + 512];

    red[t] = v0 + v1 + v2;
    __syncthreads();
    for (int off = 128; off; off >>= 1) {
        if (t < off) red[t] += red[t + off];
        __syncthreads();
    }
    const float mu = red[0] * (1.f / 768.f);
    __syncthreads();

    float d0 = v0 - mu, d1 = v1 - mu, d2 = v2 - mu;
    red[t] = d0 * d0 + d1 * d1 + d2 * d2;
    __syncthreads();
    for (int off = 128; off; off >>= 1) {
        if (t < off) red[t] += red[t + off];
        __syncthreads();
    }
    const float var = red[0] * (1.f / 768.f);
    const float rs = rsqrtf(var + 1e-12f);

    const float y0 = d0 * rs * gw[t] + bw[t];
    const float y1 = d1 * rs * gw[t + 256] + bw[t + 256];
    const float y2 = d2 * rs * gw[t + 512] + bw[t + 512];
    float* y = out + row * D_MODEL;
    y[t] = y0; y[t + 256] = y1; y[t + 512] = y2;
    if (out_bf) {
        unsigned short* yb = out_bf + row * D_MODEL;
        yb[t] = f2bf(y0); yb[t + 256] = f2bf(y1); yb[t + 512] = f2bf(y2);
    }
}

// ---------------------------------------------------------------------------
extern "C" void kernel_launch(void* const* d_in, const int* in_sizes, int n_in,
                              void* d_out, int out_size, void* d_ws, size_t ws_size,
                              hipStream_t stream)
{
    const float* hid  = (const float*)d_in[0];
    const float* am   = (const float*)d_in[1];
    const float* Wq   = (const float*)d_in[2];
    const float* bq   = (const float*)d_in[3];
    const float* Wk   = (const float*)d_in[4];
    const float* bk   = (const float*)d_in[5];
    const float* Wv   = (const float*)d_in[6];
    const float* bv   = (const float*)d_in[7];
    const float* Wo   = (const float*)d_in[8];
    const float* bo   = (const float*)d_in[9];
    const float* ln1g = (const float*)d_in[10];
    const float* ln1b = (const float*)d_in[11];
    const float* Wi   = (const float*)d_in[12];
    const float* bi   = (const float*)d_in[13];
    const float* Wo2  = (const float*)d_in[14];
    const float* bo2  = (const float*)d_in[15];
    const float* ln2g = (const float*)d_in[16];
    const float* ln2b = (const float*)d_in[17];

    const long M  = (long)B_SZ * S_LEN;                 // 8192
    const long NQ = (long)B_SZ * NHEAD * S_LEN * DH;    // 6291456

    unsigned short* W16 = (unsigned short*)d_ws;
    unsigned short* qb   = W16;             // bf16 (B,NH,S,DH)
    unsigned short* kb   = W16 + NQ;
    unsigned short* vb   = W16 + 2 * NQ;
    unsigned short* vtb  = W16 + 3 * NQ;    // bf16 (B,NH,DH,S)
    unsigned short* ctxb = W16 + 4 * NQ;    // bf16 (B,S,768)
    unsigned short* hidb = W16 + 5 * NQ;    // bf16 hidden
    unsigned short* wqt  = W16 + 6 * NQ;
    unsigned short* wkt  = wqt + 589824;
    unsigned short* wvt  = wkt + 589824;
    unsigned short* wot  = wvt + 589824;
    unsigned short* wit  = wot + 589824;    // 2359296
    unsigned short* wo2t = wit + 2359296;   // 2359296
    float* tmp = (float*)(W16 + 44826624);  // attn_out fp32
    // aliases over dead regions:
    unsigned short* interb = W16;                        // over qb..vtb (4NQ)
    unsigned short* attnb  = hidb;                       // over hidb (dead)
    float* tmp2 = (float*)(W16 + 4 * NQ);                // over ctxb+hidb
    (void)ws_size; (void)in_sizes; (void)n_in; (void)out_size;

    transpose_k<<<dim3(24, 24), dim3(32, 8), 0, stream>>>(Wq, wqt, 768, 768);
    transpose_k<<<dim3(24, 24), dim3(32, 8), 0, stream>>>(Wk, wkt, 768, 768);
    transpose_k<<<dim3(24, 24), dim3(32, 8), 0, stream>>>(Wv, wvt, 768, 768);
    transpose_k<<<dim3(24, 24), dim3(32, 8), 0, stream>>>(Wo, wot, 768, 768);
    transpose_k<<<dim3(96, 24), dim3(32, 8), 0, stream>>>(Wi, wit, 768, 3072);
    transpose_k<<<dim3(24, 96), dim3(32, 8), 0, stream>>>(Wo2, wo2t, 3072, 768);
    conv_k<<<dim3((NQ / 4 + 255) / 256), dim3(256), 0, stream>>>(hid, hidb, NQ);

    dim3 blk(256);
    dim3 g768(6, 64), g3072(24, 64);

    gemm_bf<2><<<g768, blk, 0, stream>>>(hidb, wqt, bq, nullptr, qb, M, 768, 768, 0.125f);
    gemm_bf<2><<<g768, blk, 0, stream>>>(hidb, wkt, bk, nullptr, kb, M, 768, 768, 1.f);
    gemm_bf<2><<<g768, blk, 0, stream>>>(hidb, wvt, bv, nullptr, vb, M, 768, 768, 1.f);

    vt_k<<<dim3(128, 24), blk, 0, stream>>>(vb, vtb);

    band_mfma_k<<<dim3(768), blk, 0, stream>>>(qb, kb, vtb, am, ctxb);
    glob_attn_k<<<dim3(768), blk, 0, stream>>>(qb, kb, vb, am, ctxb);

    gemm_bf<0><<<g768, blk, 0, stream>>>(ctxb, wot, bo, hid, tmp, M, 768, 768, 1.f);
    ln_k<<<dim3(M), blk, 0, stream>>>(tmp, tmp, attnb, ln1g, ln1b);

    gemm_bf<1><<<g3072, blk, 0, stream>>>(attnb, wit, bi, nullptr, interb, M, 3072, 768, 1.f);

    gemm_bf<0><<<g768, blk, 0, stream>>>(interb, wo2t, bo2, tmp, tmp2, M, 768, 3072, 1.f);
    ln_k<<<dim3(M), blk, 0, stream>>>(tmp2, (float*)d_out, nullptr, ln2g, ln2b);
}

// Round 5
// 511.660 us; speedup vs baseline: 5.2392x; 1.2275x over previous
//
#include <hip/hip_runtime.h>
#include <math.h>

#define NHEAD 12
#define DH 64
#define S_LEN 4096
#define B_SZ 2
#define D_MODEL 768
#define FF_DIM 3072
#define WINSZ 128
#define NGLB 32
#define NEGV -1e9f

typedef __attribute__((ext_vector_type(8))) short bf16x8;
typedef __attribute__((ext_vector_type(4))) float floatx4;

__device__ __forceinline__ unsigned short f2bf(float x) {
    union { float f; unsigned u; } v; v.f = x;
    unsigned r = v.u + 0x7fffu + ((v.u >> 16) & 1u);
    return (unsigned short)(r >> 16);
}
__device__ __forceinline__ float bf2f(unsigned short x) {
    union { unsigned u; float f; } v; v.u = ((unsigned)x) << 16;
    return v.f;
}

__device__ __forceinline__ void async_copy16(const unsigned short* g, unsigned short* l) {
    __builtin_amdgcn_global_load_lds(
        (const __attribute__((address_space(1))) void*)g,
        (__attribute__((address_space(3))) void*)l, 16, 0, 0);
}

// ---------------------------------------------------------------------------
// fp32 -> bf16 elementwise
// ---------------------------------------------------------------------------
__global__ __launch_bounds__(256) void conv_k(
    const float* __restrict__ x, unsigned short* __restrict__ y, long n)
{
    long i = ((long)blockIdx.x * 256 + threadIdx.x) * 4;
    if (i >= n) return;
    float4 v = *(const float4*)(x + i);
    ushort4 o;
    o.x = f2bf(v.x); o.y = f2bf(v.y); o.z = f2bf(v.z); o.w = f2bf(v.w);
    *(ushort4*)(y + i) = o;
}

// ---------------------------------------------------------------------------
// W (KxN fp32) -> WT (NxK bf16)
// ---------------------------------------------------------------------------
__global__ __launch_bounds__(256) void transpose_k(
    const float* __restrict__ W, unsigned short* __restrict__ WT, int K, int N)
{
    __shared__ float tile[32][33];
    const int tx = threadIdx.x, ty = threadIdx.y;
    const int n0 = blockIdx.x * 32, k0 = blockIdx.y * 32;
#pragma unroll
    for (int i = 0; i < 4; ++i)
        tile[ty + 8 * i][tx] = W[(long)(k0 + ty + 8 * i) * N + n0 + tx];
    __syncthreads();
#pragma unroll
    for (int i = 0; i < 4; ++i)
        WT[(long)(n0 + ty + 8 * i) * K + k0 + tx] = f2bf(tile[tx][ty + 8 * i]);
}

// ---------------------------------------------------------------------------
// V (B,NH,S,DH) bf16 -> Vt (B,NH,DH,S) bf16
// ---------------------------------------------------------------------------
__global__ __launch_bounds__(256) void vt_k(
    const unsigned short* __restrict__ v, unsigned short* __restrict__ vt)
{
    const int bh = blockIdx.y;
    const int s0 = blockIdx.x * 32;
    const int w = threadIdx.x >> 6, lane = threadIdx.x & 63;
    const unsigned short* src = v + ((long)bh * S_LEN + s0 + w * 8) * DH + lane;
    unsigned short r[8];
#pragma unroll
    for (int j = 0; j < 8; ++j) r[j] = src[j * DH];
    unsigned short* dst = vt + ((long)bh * DH + lane) * S_LEN + s0 + w * 8;
    ushort4 lo, hi;
    lo.x = r[0]; lo.y = r[1]; lo.z = r[2]; lo.w = r[3];
    hi.x = r[4]; hi.y = r[5]; hi.z = r[6]; hi.w = r[7];
    *(ushort4*)dst = lo;
    *(ushort4*)(dst + 4) = hi;
}

// ---------------------------------------------------------------------------
// bf16 MFMA GEMM (m97-style): C = epi(A @ BT^T + bias)
// ---------------------------------------------------------------------------
template <int EPI>
__global__ __launch_bounds__(256) void gemm_bf(
    const unsigned short* __restrict__ A, const unsigned short* __restrict__ BT,
    const float* __restrict__ bias, const float* __restrict__ resid,
    void* __restrict__ out, int M, int N, int K, float scale)
{
    __shared__ unsigned short As[128 * 32];
    __shared__ unsigned short Bs[128 * 32];
    const int tid = threadIdx.x;
    const int wave = tid >> 6, lane = tid & 63;
    const int m0 = blockIdx.y * 128, n0 = blockIdx.x * 128;
    const int wr = (wave >> 1) * 64, wc = (wave & 1) * 64;

    floatx4 acc[4][4];
#pragma unroll
    for (int i = 0; i < 4; ++i)
#pragma unroll
        for (int j = 0; j < 4; ++j) acc[i][j] = (floatx4){0.f, 0.f, 0.f, 0.f};

    const int srow = lane >> 2;
    const int schk = (lane & 3) * 8;
    const int r = lane & 15;
    const int q8 = (lane >> 4) * 8;

    for (int k0 = 0; k0 < K; k0 += 32) {
#pragma unroll
        for (int gi = 0; gi < 2; ++gi) {
            const int g = wave * 2 + gi;
            async_copy16(A + (long)(m0 + g * 16 + srow) * K + k0 + schk, &As[g * 512]);
            async_copy16(BT + (long)(n0 + g * 16 + srow) * K + k0 + schk, &Bs[g * 512]);
        }
        __syncthreads();

        bf16x8 af[4], bfr[4];
#pragma unroll
        for (int i = 0; i < 4; ++i) {
            af[i]  = *(const bf16x8*)&As[(wr + i * 16 + r) * 32 + q8];
            bfr[i] = *(const bf16x8*)&Bs[(wc + i * 16 + r) * 32 + q8];
        }
#pragma unroll
        for (int i = 0; i < 4; ++i)
#pragma unroll
            for (int j = 0; j < 4; ++j)
                acc[i][j] = __builtin_amdgcn_mfma_f32_16x16x32_bf16(
                    af[i], bfr[j], acc[i][j], 0, 0, 0);
        __syncthreads();
    }

    const int col_l = lane & 15, row_l = (lane >> 4) * 4;
#pragma unroll
    for (int i = 0; i < 4; ++i) {
#pragma unroll
        for (int j = 0; j < 4; ++j) {
            const int n = n0 + wc + j * 16 + col_l;
            const float bv = bias[n];
#pragma unroll
            for (int rg = 0; rg < 4; ++rg) {
                const int m = m0 + wr + i * 16 + row_l + rg;
                float v = acc[i][j][rg] + bv;
                if (EPI == 0) {
                    ((float*)out)[(long)m * N + n] = v + resid[(long)m * N + n];
                } else if (EPI == 1) {
                    v = 0.5f * v * (1.f + erff(v * 0.70710678118654752f));
                    ((unsigned short*)out)[(long)m * N + n] = f2bf(v);
                } else {
                    const int bb = m >> 12, s = m & 4095;
                    const int hh = n >> 6, dh = n & 63;
                    ((unsigned short*)out)[(((long)bb * NHEAD + hh) * S_LEN + s) * DH + dh] =
                        f2bf(v * scale);
                }
            }
        }
    }
}

// ---------------------------------------------------------------------------
// MFMA band attention. One block per (b,h,chunk); 4 waves x 32 queries.
// ---------------------------------------------------------------------------
__global__ __launch_bounds__(256) void band_mfma_k(
    const unsigned short* __restrict__ q, const unsigned short* __restrict__ k,
    const unsigned short* __restrict__ vt, const float* __restrict__ am,
    unsigned short* __restrict__ ctx)
{
    __shared__ unsigned short Ks[32 * 72];      // [key][dim], stride 72 u16
    __shared__ unsigned short Vs[64 * 40];      // [dim][key], stride 40 u16
    __shared__ unsigned short Ps[4][32 * 40];   // per wave [q][key], stride 40

    const int blk = blockIdx.x;
    const int c = blk & 31;
    const int h = (blk >> 5) % NHEAD;
    const int b = blk / (32 * NHEAD);
    const int tid = threadIdx.x;
    const int wave = tid >> 6, lane = tid & 63;
    const long bh = (long)b * NHEAD + h;

    const unsigned short* kh  = k + bh * S_LEN * DH;
    const unsigned short* vth = vt + bh * (long)DH * S_LEN;
    const float* amb = am + (long)b * S_LEN;

    const int q0 = c * WINSZ + wave * 32;
    const int ln15 = lane & 15, ln4 = lane >> 4;

    bf16x8 qf[2][2];
#pragma unroll
    for (int nt = 0; nt < 2; ++nt)
#pragma unroll
        for (int ks = 0; ks < 2; ++ks)
            qf[nt][ks] = *(const bf16x8*)(q + (bh * S_LEN + q0 + nt * 16 + ln15) * DH
                                          + ks * 32 + ln4 * 8);

    floatx4 o[4][2];
#pragma unroll
    for (int mt = 0; mt < 4; ++mt)
#pragma unroll
        for (int nt = 0; nt < 2; ++nt) o[mt][nt] = (floatx4){0.f, 0.f, 0.f, 0.f};
    float m_r[2] = {-1e30f, -1e30f}, l_r[2] = {0.f, 0.f};

    const int sk_key = tid >> 3, sk_ch = tid & 7;
    const int sv_dim = tid & 63, sv_ch = tid >> 6;
    const bf16x8 zero8 = {0, 0, 0, 0, 0, 0, 0, 0};

    for (int tile = 0; tile < 13; ++tile) {
        const bool glob = (tile == 12);
        const int kbase = glob ? 0 : (c * WINSZ - WINSZ + tile * 32);

        __syncthreads();
        {
            int kpos = kbase + sk_key;
            bf16x8 val = zero8;
            if ((unsigned)kpos < (unsigned)S_LEN)
                val = *(const bf16x8*)(kh + (long)kpos * DH + sk_ch * 8);
            *(bf16x8*)(&Ks[sk_key * 72 + sk_ch * 8]) = val;
        }
        {
            int kc = kbase + sv_ch * 8;
            bf16x8 val = zero8;
            if (kc >= 0 && kc + 8 <= S_LEN)
                val = *(const bf16x8*)(vth + (long)sv_dim * S_LEN + kc);
            *(bf16x8*)(&Vs[sv_dim * 40 + sv_ch * 8]) = val;
        }
        __syncthreads();

        bf16x8 ak[2][2];
#pragma unroll
        for (int mt = 0; mt < 2; ++mt)
#pragma unroll
            for (int ks = 0; ks < 2; ++ks)
                ak[mt][ks] = *(const bf16x8*)(&Ks[(mt * 16 + ln15) * 72 + ks * 32 + ln4 * 8]);

        floatx4 s[2][2];
#pragma unroll
        for (int mt = 0; mt < 2; ++mt)
#pragma unroll
            for (int nt = 0; nt < 2; ++nt) {
                floatx4 acc = (floatx4){0.f, 0.f, 0.f, 0.f};
                acc = __builtin_amdgcn_mfma_f32_16x16x32_bf16(ak[mt][0], qf[nt][0], acc, 0, 0, 0);
                acc = __builtin_amdgcn_mfma_f32_16x16x32_bf16(ak[mt][1], qf[nt][1], acc, 0, 0, 0);
                s[mt][nt] = acc;
            }

#pragma unroll
        for (int mt = 0; mt < 2; ++mt) {
            const int kp0 = kbase + mt * 16 + ln4 * 4;
#pragma unroll
            for (int rg = 0; rg < 4; ++rg) {
                const int kpos = kp0 + rg;
                const bool kin = (unsigned)kpos < (unsigned)S_LEN;
                const float amv = kin ? amb[kpos] : 0.f;
#pragma unroll
                for (int nt = 0; nt < 2; ++nt) {
                    const int qpos = q0 + nt * 16 + ln15;
                    const int dlt = kpos > qpos ? kpos - qpos : qpos - kpos;
                    const bool valid = glob || (kpos >= NGLB && kin && dlt <= WINSZ);
                    s[mt][nt][rg] = valid ? s[mt][nt][rg] + amv : NEGV;
                }
            }
        }

        float alpha[2];
#pragma unroll
        for (int nt = 0; nt < 2; ++nt) {
            float mx = s[0][nt][0];
#pragma unroll
            for (int rg = 1; rg < 4; ++rg) mx = fmaxf(mx, s[0][nt][rg]);
#pragma unroll
            for (int rg = 0; rg < 4; ++rg) mx = fmaxf(mx, s[1][nt][rg]);
            mx = fmaxf(mx, __shfl_xor(mx, 16));
            mx = fmaxf(mx, __shfl_xor(mx, 32));
            const float mn = fmaxf(m_r[nt], mx);
            alpha[nt] = __expf(m_r[nt] - mn);
            m_r[nt] = mn;
        }

#pragma unroll
        for (int nt = 0; nt < 2; ++nt) {
            float sum = 0.f;
#pragma unroll
            for (int mt = 0; mt < 2; ++mt) {
                ushort4 pk;
#pragma unroll
                for (int rg = 0; rg < 4; ++rg) {
                    const float p = __expf(s[mt][nt][rg] - m_r[nt]);
                    sum += p;
                    ((unsigned short*)&pk)[rg] = f2bf(p);
                }
                *(ushort4*)(&Ps[wave][(nt * 16 + ln15) * 40 + mt * 16 + ln4 * 4]) = pk;
            }
            sum += __shfl_xor(sum, 16);
            sum += __shfl_xor(sum, 32);
            l_r[nt] = l_r[nt] * alpha[nt] + sum;
        }

#pragma unroll
        for (int mt = 0; mt < 4; ++mt)
#pragma unroll
            for (int nt = 0; nt < 2; ++nt)
#pragma unroll
                for (int rg = 0; rg < 4; ++rg) o[mt][nt][rg] *= alpha[nt];

        bf16x8 av[4], bp[2];
#pragma unroll
        for (int mt = 0; mt < 4; ++mt)
            av[mt] = *(const bf16x8*)(&Vs[(mt * 16 + ln15) * 40 + ln4 * 8]);
#pragma unroll
        for (int nt = 0; nt < 2; ++nt)
            bp[nt] = *(const bf16x8*)(&Ps[wave][(nt * 16 + ln15) * 40 + ln4 * 8]);
#pragma unroll
        for (int mt = 0; mt < 4; ++mt)
#pragma unroll
            for (int nt = 0; nt < 2; ++nt)
                o[mt][nt] = __builtin_amdgcn_mfma_f32_16x16x32_bf16(
                    av[mt], bp[nt], o[mt][nt], 0, 0, 0);
    }

    const float inv0 = 1.f / l_r[0], inv1 = 1.f / l_r[1];
#pragma unroll
    for (int nt = 0; nt < 2; ++nt) {
        const float inv = nt ? inv1 : inv0;
        const long row = (long)b * S_LEN + q0 + nt * 16 + ln15;
#pragma unroll
        for (int mt = 0; mt < 4; ++mt) {
            ushort4 ov;
#pragma unroll
            for (int rg = 0; rg < 4; ++rg)
                ((unsigned short*)&ov)[rg] = f2bf(o[mt][nt][rg] * inv);
            *(ushort4*)(ctx + row * D_MODEL + h * DH + mt * 16 + ln4 * 4) = ov;
        }
    }
}

// ---------------------------------------------------------------------------
// MFMA global-query attention. One block per (b,h); 8 waves x 512 keys/iter.
// S^T = K·Q^T (m=key, n=query=32), per-wave online softmax over its keys,
// O^T += V^T·P^T; cross-wave merge of (m,l,O) via LDS at the end.
// Overwrites ctx rows 0..NG-1 (stream-ordered after band_mfma_k).
// ---------------------------------------------------------------------------
__global__ __launch_bounds__(512) void glob_mfma_k(
    const unsigned short* __restrict__ q, const unsigned short* __restrict__ k,
    const unsigned short* __restrict__ vt, const float* __restrict__ am,
    unsigned short* __restrict__ ctx)
{
    __shared__ unsigned short Ps[8][32 * 72];   // per wave [q=32][key=64+8pad]
    __shared__ float Om[64 * 36];               // merged O^T [dim][q]
    __shared__ float mW[8][32], lW[8][32], lTot[32];

    const int bh = blockIdx.x;                  // B*NH = 24
    const int b = bh / NHEAD, h = bh % NHEAD;
    const int tid = threadIdx.x;
    const int wave = tid >> 6, lane = tid & 63;
    const int ln15 = lane & 15, ln4 = lane >> 4;

    const unsigned short* kh  = k + (long)bh * S_LEN * DH;
    const unsigned short* vth = vt + (long)bh * DH * S_LEN;
    const float* amb = am + (long)b * S_LEN;

    // Q B-fragments: 32 global queries (rows 0..31)
    bf16x8 qf[2][2];
#pragma unroll
    for (int nt = 0; nt < 2; ++nt)
#pragma unroll
        for (int ks = 0; ks < 2; ++ks)
            qf[nt][ks] = *(const bf16x8*)(q + ((long)bh * S_LEN + nt * 16 + ln15) * DH
                                          + ks * 32 + ln4 * 8);

    floatx4 o[4][2];
#pragma unroll
    for (int mt = 0; mt < 4; ++mt)
#pragma unroll
        for (int nt = 0; nt < 2; ++nt) o[mt][nt] = (floatx4){0.f, 0.f, 0.f, 0.f};
    float m_r[2] = {-1e30f, -1e30f}, l_r[2] = {0.f, 0.f};

    for (int it = 0; it < 8; ++it) {
        const int kbase = it * 512 + wave * 64;

        // K A-fragments direct from global (coalesced within 16-row groups)
        bf16x8 ak[4][2];
#pragma unroll
        for (int mt = 0; mt < 4; ++mt)
#pragma unroll
            for (int ks = 0; ks < 2; ++ks)
                ak[mt][ks] = *(const bf16x8*)(kh + (long)(kbase + mt * 16 + ln15) * DH
                                              + ks * 32 + ln4 * 8);

        floatx4 s[4][2];
#pragma unroll
        for (int mt = 0; mt < 4; ++mt)
#pragma unroll
            for (int nt = 0; nt < 2; ++nt) {
                floatx4 acc = (floatx4){0.f, 0.f, 0.f, 0.f};
                acc = __builtin_amdgcn_mfma_f32_16x16x32_bf16(ak[mt][0], qf[nt][0], acc, 0, 0, 0);
                acc = __builtin_amdgcn_mfma_f32_16x16x32_bf16(ak[mt][1], qf[nt][1], acc, 0, 0, 0);
                s[mt][nt] = acc;
            }

        // + attention mask (per key)
#pragma unroll
        for (int mt = 0; mt < 4; ++mt) {
            const int kp0 = kbase + mt * 16 + ln4 * 4;
#pragma unroll
            for (int rg = 0; rg < 4; ++rg) {
                const float amv = amb[kp0 + rg];
#pragma unroll
                for (int nt = 0; nt < 2; ++nt) s[mt][nt][rg] += amv;
            }
        }

        // per-wave online softmax (per query column)
        float alpha[2];
#pragma unroll
        for (int nt = 0; nt < 2; ++nt) {
            float mx = s[0][nt][0];
#pragma unroll
            for (int mt = 0; mt < 4; ++mt)
#pragma unroll
                for (int rg = 0; rg < 4; ++rg) mx = fmaxf(mx, s[mt][nt][rg]);
            mx = fmaxf(mx, __shfl_xor(mx, 16));
            mx = fmaxf(mx, __shfl_xor(mx, 32));
            const float mn = fmaxf(m_r[nt], mx);
            alpha[nt] = __expf(m_r[nt] - mn);
            m_r[nt] = mn;
        }

#pragma unroll
        for (int nt = 0; nt < 2; ++nt) {
            float sum = 0.f;
#pragma unroll
            for (int mt = 0; mt < 4; ++mt) {
                ushort4 pk;
#pragma unroll
                for (int rg = 0; rg < 4; ++rg) {
                    const float p = __expf(s[mt][nt][rg] - m_r[nt]);
                    sum += p;
                    ((unsigned short*)&pk)[rg] = f2bf(p);
                }
                *(ushort4*)(&Ps[wave][(nt * 16 + ln15) * 72 + mt * 16 + ln4 * 4]) = pk;
            }
            sum += __shfl_xor(sum, 16);
            sum += __shfl_xor(sum, 32);
            l_r[nt] = l_r[nt] * alpha[nt] + sum;
        }

#pragma unroll
        for (int mt = 0; mt < 4; ++mt)
#pragma unroll
            for (int nt = 0; nt < 2; ++nt)
#pragma unroll
                for (int rg = 0; rg < 4; ++rg) o[mt][nt][rg] *= alpha[nt];

        // O^T += V^T · P^T  (V^T A-fragments direct from global)
        bf16x8 av[4][2], bp[2][2];
#pragma unroll
        for (int mt = 0; mt < 4; ++mt)
#pragma unroll
            for (int ks = 0; ks < 2; ++ks)
                av[mt][ks] = *(const bf16x8*)(vth + (long)(mt * 16 + ln15) * S_LEN
                                              + kbase + ks * 32 + ln4 * 8);
#pragma unroll
        for (int nt = 0; nt < 2; ++nt)
#pragma unroll
            for (int ks = 0; ks < 2; ++ks)
                bp[nt][ks] = *(const bf16x8*)(&Ps[wave][(nt * 16 + ln15) * 72
                                              + ks * 32 + ln4 * 8]);
#pragma unroll
        for (int mt = 0; mt < 4; ++mt)
#pragma unroll
            for (int nt = 0; nt < 2; ++nt) {
                o[mt][nt] = __builtin_amdgcn_mfma_f32_16x16x32_bf16(
                    av[mt][0], bp[nt][0], o[mt][nt], 0, 0, 0);
                o[mt][nt] = __builtin_amdgcn_mfma_f32_16x16x32_bf16(
                    av[mt][1], bp[nt][1], o[mt][nt], 0, 0, 0);
            }
    }

    // ---- cross-wave merge ----
    if (ln4 == 0) {
#pragma unroll
        for (int nt = 0; nt < 2; ++nt) {
            mW[wave][nt * 16 + ln15] = m_r[nt];
            lW[wave][nt * 16 + ln15] = l_r[nt];
        }
    }
    for (int i = tid; i < 64 * 36; i += 512) Om[i] = 0.f;
    __syncthreads();

    float f[2];
#pragma unroll
    for (int nt = 0; nt < 2; ++nt) {
        const int qq = nt * 16 + ln15;
        float mt_ = mW[0][qq];
#pragma unroll
        for (int w = 1; w < 8; ++w) mt_ = fmaxf(mt_, mW[w][qq]);
        float lt = 0.f;
#pragma unroll
        for (int w = 0; w < 8; ++w) lt += __expf(mW[w][qq] - mt_) * lW[w][qq];
        f[nt] = __expf(m_r[nt] - mt_);
        if (wave == 0 && ln4 == 0) lTot[qq] = lt;
    }
#pragma unroll
    for (int mt = 0; mt < 4; ++mt)
#pragma unroll
        for (int nt = 0; nt < 2; ++nt)
#pragma unroll
            for (int rg = 0; rg < 4; ++rg) o[mt][nt][rg] *= f[nt];

    for (int wv = 0; wv < 8; ++wv) {
        if (wave == wv) {
#pragma unroll
            for (int mt = 0; mt < 4; ++mt)
#pragma unroll
                for (int nt = 0; nt < 2; ++nt)
#pragma unroll
                    for (int rg = 0; rg < 4; ++rg)
                        Om[(mt * 16 + ln4 * 4 + rg) * 36 + nt * 16 + ln15] += o[mt][nt][rg];
        }
        __syncthreads();
    }

    // write 32 queries x 64 dims
    const int qq = tid >> 4, d0 = (tid & 15) * 4;
    const float inv = 1.f / lTot[qq];
    ushort4 ov;
#pragma unroll
    for (int i = 0; i < 4; ++i)
        ((unsigned short*)&ov)[i] = f2bf(Om[(d0 + i) * 36 + qq] * inv);
    *(ushort4*)(ctx + ((long)b * S_LEN + qq) * D_MODEL + h * DH + d0) = ov;
}

// ---------------------------------------------------------------------------
// LayerNorm rows of 768; optional bf16 copy.
// ---------------------------------------------------------------------------
__global__ __launch_bounds__(256) void ln_k(
    const float* __restrict__ in, float* __restrict__ out,
    unsigned short* __restrict__ out_bf,
    const float* __restrict__ gw, const float* __restrict__ bw)
{
    __shared__ float red[256];
    const long row = blockIdx.x;
    const float* x = in + row * D_MODEL;
    const int t = threadIdx.x;
    float v0 = x[t], v1 = x[t + 256], v2 = x[t + 512];

    red[t] = v0 + v1 + v2;
    __syncthreads();
    for (int off = 128; off; off >>= 1) {
        if (t < off) red[t] += red[t + off];
        __syncthreads();
    }
    const float mu = red[0] * (1.f / 768.f);
    __syncthreads();

    float d0 = v0 - mu, d1 = v1 - mu, d2 = v2 - mu;
    red[t] = d0 * d0 + d1 * d1 + d2 * d2;
    __syncthreads();
    for (int off = 128; off; off >>= 1) {
        if (t < off) red[t] += red[t + off];
        __syncthreads();
    }
    const float var = red[0] * (1.f / 768.f);
    const float rs = rsqrtf(var + 1e-12f);

    const float y0 = d0 * rs * gw[t] + bw[t];
    const float y1 = d1 * rs * gw[t + 256] + bw[t + 256];
    const float y2 = d2 * rs * gw[t + 512] + bw[t + 512];
    float* y = out + row * D_MODEL;
    y[t] = y0; y[t + 256] = y1; y[t + 512] = y2;
    if (out_bf) {
        unsigned short* yb = out_bf + row * D_MODEL;
        yb[t] = f2bf(y0); yb[t + 256] = f2bf(y1); yb[t + 512] = f2bf(y2);
    }
}

// ---------------------------------------------------------------------------
extern "C" void kernel_launch(void* const* d_in, const int* in_sizes, int n_in,
                              void* d_out, int out_size, void* d_ws, size_t ws_size,
                              hipStream_t stream)
{
    const float* hid  = (const float*)d_in[0];
    const float* am   = (const float*)d_in[1];
    const float* Wq   = (const float*)d_in[2];
    const float* bq   = (const float*)d_in[3];
    const float* Wk   = (const float*)d_in[4];
    const float* bk   = (const float*)d_in[5];
    const float* Wv   = (const float*)d_in[6];
    const float* bv   = (const float*)d_in[7];
    const float* Wo   = (const float*)d_in[8];
    const float* bo   = (const float*)d_in[9];
    const float* ln1g = (const float*)d_in[10];
    const float* ln1b = (const float*)d_in[11];
    const float* Wi   = (const float*)d_in[12];
    const float* bi   = (const float*)d_in[13];
    const float* Wo2  = (const float*)d_in[14];
    const float* bo2  = (const float*)d_in[15];
    const float* ln2g = (const float*)d_in[16];
    const float* ln2b = (const float*)d_in[17];

    const long M  = (long)B_SZ * S_LEN;                 // 8192
    const long NQ = (long)B_SZ * NHEAD * S_LEN * DH;    // 6291456

    unsigned short* W16 = (unsigned short*)d_ws;
    unsigned short* qb   = W16;             // bf16 (B,NH,S,DH)
    unsigned short* kb   = W16 + NQ;
    unsigned short* vb   = W16 + 2 * NQ;
    unsigned short* vtb  = W16 + 3 * NQ;    // bf16 (B,NH,DH,S)
    unsigned short* ctxb = W16 + 4 * NQ;    // bf16 (B,S,768)
    unsigned short* hidb = W16 + 5 * NQ;    // bf16 hidden
    unsigned short* wqt  = W16 + 6 * NQ;
    unsigned short* wkt  = wqt + 589824;
    unsigned short* wvt  = wkt + 589824;
    unsigned short* wot  = wvt + 589824;
    unsigned short* wit  = wot + 589824;    // 2359296
    unsigned short* wo2t = wit + 2359296;   // 2359296
    float* tmp = (float*)(W16 + 44826624);  // attn_out fp32
    unsigned short* interb = W16;                        // over qb..vtb (4NQ)
    unsigned short* attnb  = hidb;                       // over hidb (dead)
    float* tmp2 = (float*)(W16 + 4 * NQ);                // over ctxb+hidb
    (void)ws_size; (void)in_sizes; (void)n_in; (void)out_size;

    transpose_k<<<dim3(24, 24), dim3(32, 8), 0, stream>>>(Wq, wqt, 768, 768);
    transpose_k<<<dim3(24, 24), dim3(32, 8), 0, stream>>>(Wk, wkt, 768, 768);
    transpose_k<<<dim3(24, 24), dim3(32, 8), 0, stream>>>(Wv, wvt, 768, 768);
    transpose_k<<<dim3(24, 24), dim3(32, 8), 0, stream>>>(Wo, wot, 768, 768);
    transpose_k<<<dim3(96, 24), dim3(32, 8), 0, stream>>>(Wi, wit, 768, 3072);
    transpose_k<<<dim3(24, 96), dim3(32, 8), 0, stream>>>(Wo2, wo2t, 3072, 768);
    conv_k<<<dim3((NQ / 4 + 255) / 256), dim3(256), 0, stream>>>(hid, hidb, NQ);

    dim3 blk(256);
    dim3 g768(6, 64), g3072(24, 64);

    gemm_bf<2><<<g768, blk, 0, stream>>>(hidb, wqt, bq, nullptr, qb, M, 768, 768, 0.125f);
    gemm_bf<2><<<g768, blk, 0, stream>>>(hidb, wkt, bk, nullptr, kb, M, 768, 768, 1.f);
    gemm_bf<2><<<g768, blk, 0, stream>>>(hidb, wvt, bv, nullptr, vb, M, 768, 768, 1.f);

    vt_k<<<dim3(128, 24), blk, 0, stream>>>(vb, vtb);

    band_mfma_k<<<dim3(768), blk, 0, stream>>>(qb, kb, vtb, am, ctxb);
    glob_mfma_k<<<dim3(B_SZ * NHEAD), dim3(512), 0, stream>>>(qb, kb, vtb, am, ctxb);

    gemm_bf<0><<<g768, blk, 0, stream>>>(ctxb, wot, bo, hid, tmp, M, 768, 768, 1.f);
    ln_k<<<dim3(M), blk, 0, stream>>>(tmp, tmp, attnb, ln1g, ln1b);

    gemm_bf<1><<<g3072, blk, 0, stream>>>(attnb, wit, bi, nullptr, interb, M, 3072, 768, 1.f);

    gemm_bf<0><<<g768, blk, 0, stream>>>(interb, wo2t, bo2, tmp, tmp2, M, 768, 3072, 1.f);
    ln_k<<<dim3(M), blk, 0, stream>>>(tmp2, (float*)d_out, nullptr, ln2g, ln2b);
}

// Round 7
// 473.813 us; speedup vs baseline: 5.6577x; 1.0799x over previous
//
#include <hip/hip_runtime.h>
#include <math.h>

#define NHEAD 12
#define DH 64
#define S_LEN 4096
#define B_SZ 2
#define D_MODEL 768
#define FF_DIM 3072
#define WINSZ 128
#define NGLB 32
#define NEGV -1e9f
#define NQC 6291456L

typedef __attribute__((ext_vector_type(8))) short bf16x8;
typedef __attribute__((ext_vector_type(4))) float floatx4;

__device__ __forceinline__ unsigned short f2bf(float x) {
    union { float f; unsigned u; } v; v.f = x;
    unsigned r = v.u + 0x7fffu + ((v.u >> 16) & 1u);
    return (unsigned short)(r >> 16);
}
__device__ __forceinline__ float bf2f(unsigned short x) {
    union { unsigned u; float f; } v; v.u = ((unsigned)x) << 16;
    return v.f;
}

__device__ __forceinline__ void async_copy16(const unsigned short* g, unsigned short* l) {
    __builtin_amdgcn_global_load_lds(
        (const __attribute__((address_space(1))) void*)g,
        (__attribute__((address_space(3))) void*)l, 16, 0, 0);
}

// ---------------------------------------------------------------------------
// fp32 -> bf16 elementwise
// ---------------------------------------------------------------------------
__global__ __launch_bounds__(256) void conv_k(
    const float* __restrict__ x, unsigned short* __restrict__ y, long n)
{
    long i = ((long)blockIdx.x * 256 + threadIdx.x) * 4;
    if (i >= n) return;
    float4 v = *(const float4*)(x + i);
    ushort4 o;
    o.x = f2bf(v.x); o.y = f2bf(v.y); o.z = f2bf(v.z); o.w = f2bf(v.w);
    *(ushort4*)(y + i) = o;
}

// ---------------------------------------------------------------------------
// concat 3 x 768 biases -> 2304
// ---------------------------------------------------------------------------
__global__ __launch_bounds__(256) void bcat_k(
    const float* __restrict__ a, const float* __restrict__ b,
    const float* __restrict__ c, float* __restrict__ o)
{
    int i = blockIdx.x * 256 + threadIdx.x;
    if (i < 768) o[i] = a[i];
    else if (i < 1536) o[i] = b[i - 768];
    else if (i < 2304) o[i] = c[i - 1536];
}

// ---------------------------------------------------------------------------
// W (KxN fp32) -> WT (NxK bf16)
// ---------------------------------------------------------------------------
__global__ __launch_bounds__(256) void transpose_k(
    const float* __restrict__ W, unsigned short* __restrict__ WT, int K, int N)
{
    __shared__ float tile[32][33];
    const int tx = threadIdx.x, ty = threadIdx.y;
    const int n0 = blockIdx.x * 32, k0 = blockIdx.y * 32;
#pragma unroll
    for (int i = 0; i < 4; ++i)
        tile[ty + 8 * i][tx] = W[(long)(k0 + ty + 8 * i) * N + n0 + tx];
    __syncthreads();
#pragma unroll
    for (int i = 0; i < 4; ++i)
        WT[(long)(n0 + ty + 8 * i) * K + k0 + tx] = f2bf(tile[tx][ty + 8 * i]);
}

// ---------------------------------------------------------------------------
// V (B,NH,S,DH) bf16 -> Vt (B,NH,DH,S) bf16
// ---------------------------------------------------------------------------
__global__ __launch_bounds__(256) void vt_k(
    const unsigned short* __restrict__ v, unsigned short* __restrict__ vt)
{
    const int bh = blockIdx.y;
    const int s0 = blockIdx.x * 32;
    const int w = threadIdx.x >> 6, lane = threadIdx.x & 63;
    const unsigned short* src = v + ((long)bh * S_LEN + s0 + w * 8) * DH + lane;
    unsigned short r[8];
#pragma unroll
    for (int j = 0; j < 8; ++j) r[j] = src[j * DH];
    unsigned short* dst = vt + ((long)bh * DH + lane) * S_LEN + s0 + w * 8;
    ushort4 lo, hi;
    lo.x = r[0]; lo.y = r[1]; lo.z = r[2]; lo.w = r[3];
    hi.x = r[4]; hi.y = r[5]; hi.z = r[6]; hi.w = r[7];
    *(ushort4*)dst = lo;
    *(ushort4*)(dst + 4) = hi;
}

// ---------------------------------------------------------------------------
// bf16 MFMA GEMM: C = epi(A @ BT^T + bias). 1D grid with XCD-clustered
// swizzle: id%8 -> XCD slot, so all n-blocks of an A-slab run on one XCD
// (L2-local A reuse). nx = N/128.
// EPI 0: +bias +resid(fp32) -> fp32
// EPI 1: gelu -> bf16
// EPI 2: fused QKV scatter: part=n/768 (q|k|v), Q scaled by 0.125 -> bf16
// ---------------------------------------------------------------------------
template <int EPI>
__global__ __launch_bounds__(256) void gemm_bf(
    const unsigned short* __restrict__ A, const unsigned short* __restrict__ BT,
    const float* __restrict__ bias, const float* __restrict__ resid,
    void* __restrict__ out, int M, int N, int K, int nx)
{
    __shared__ unsigned short As[128 * 32];
    __shared__ unsigned short Bs[128 * 32];
    const int tid = threadIdx.x;
    const int wave = tid >> 6, lane = tid & 63;
    const int t8 = (blockIdx.x & 7) * (gridDim.x >> 3) + (blockIdx.x >> 3);
    const int m0 = (t8 / nx) * 128, n0 = (t8 % nx) * 128;
    const int wr = (wave >> 1) * 64, wc = (wave & 1) * 64;

    floatx4 acc[4][4];
#pragma unroll
    for (int i = 0; i < 4; ++i)
#pragma unroll
        for (int j = 0; j < 4; ++j) acc[i][j] = (floatx4){0.f, 0.f, 0.f, 0.f};

    const int srow = lane >> 2;
    const int schk = (lane & 3) * 8;
    const int r = lane & 15;
    const int q8 = (lane >> 4) * 8;

    for (int k0 = 0; k0 < K; k0 += 32) {
#pragma unroll
        for (int gi = 0; gi < 2; ++gi) {
            const int g = wave * 2 + gi;
            async_copy16(A + (long)(m0 + g * 16 + srow) * K + k0 + schk, &As[g * 512]);
            async_copy16(BT + (long)(n0 + g * 16 + srow) * K + k0 + schk, &Bs[g * 512]);
        }
        __syncthreads();

        bf16x8 af[4], bfr[4];
#pragma unroll
        for (int i = 0; i < 4; ++i) {
            af[i]  = *(const bf16x8*)&As[(wr + i * 16 + r) * 32 + q8];
            bfr[i] = *(const bf16x8*)&Bs[(wc + i * 16 + r) * 32 + q8];
        }
#pragma unroll
        for (int i = 0; i < 4; ++i)
#pragma unroll
            for (int j = 0; j < 4; ++j)
                acc[i][j] = __builtin_amdgcn_mfma_f32_16x16x32_bf16(
                    af[i], bfr[j], acc[i][j], 0, 0, 0);
        __syncthreads();
    }

    const int col_l = lane & 15, row_l = (lane >> 4) * 4;
#pragma unroll
    for (int i = 0; i < 4; ++i) {
#pragma unroll
        for (int j = 0; j < 4; ++j) {
            const int n = n0 + wc + j * 16 + col_l;
            const float bv = bias[n];
#pragma unroll
            for (int rg = 0; rg < 4; ++rg) {
                const int m = m0 + wr + i * 16 + row_l + rg;
                float v = acc[i][j][rg] + bv;
                if (EPI == 0) {
                    ((float*)out)[(long)m * N + n] = v + resid[(long)m * N + n];
                } else if (EPI == 1) {
                    v = 0.5f * v * (1.f + erff(v * 0.70710678118654752f));
                    ((unsigned short*)out)[(long)m * N + n] = f2bf(v);
                } else {
                    const int bb = m >> 12, s = m & 4095;
                    const int part = n / 768;          // 0=q, 1=k, 2=v
                    const int nn = n - part * 768;
                    const int hh = nn >> 6, dh = nn & 63;
                    const float sc = (part == 0) ? 0.125f : 1.f;
                    ((unsigned short*)out)[(long)part * NQC +
                        (((long)bb * NHEAD + hh) * S_LEN + s) * DH + dh] = f2bf(v * sc);
                }
            }
        }
    }
}

// ---------------------------------------------------------------------------
// MFMA band attention. One block per (b,h,chunk); 4 waves x 32 queries.
// ---------------------------------------------------------------------------
__global__ __launch_bounds__(256) void band_mfma_k(
    const unsigned short* __restrict__ q, const unsigned short* __restrict__ k,
    const unsigned short* __restrict__ vt, const float* __restrict__ am,
    unsigned short* __restrict__ ctx)
{
    __shared__ unsigned short Ks[32 * 72];      // [key][dim], stride 72 u16
    __shared__ unsigned short Vs[64 * 40];      // [dim][key], stride 40 u16
    __shared__ unsigned short Ps[4][32 * 40];   // per wave [q][key], stride 40

    const int blk = blockIdx.x;
    const int c = blk & 31;
    const int h = (blk >> 5) % NHEAD;
    const int b = blk / (32 * NHEAD);
    const int tid = threadIdx.x;
    const int wave = tid >> 6, lane = tid & 63;
    const long bh = (long)b * NHEAD + h;

    const unsigned short* kh  = k + bh * S_LEN * DH;
    const unsigned short* vth = vt + bh * (long)DH * S_LEN;
    const float* amb = am + (long)b * S_LEN;

    const int q0 = c * WINSZ + wave * 32;
    const int ln15 = lane & 15, ln4 = lane >> 4;

    bf16x8 qf[2][2];
#pragma unroll
    for (int nt = 0; nt < 2; ++nt)
#pragma unroll
        for (int ks = 0; ks < 2; ++ks)
            qf[nt][ks] = *(const bf16x8*)(q + (bh * S_LEN + q0 + nt * 16 + ln15) * DH
                                          + ks * 32 + ln4 * 8);

    floatx4 o[4][2];
#pragma unroll
    for (int mt = 0; mt < 4; ++mt)
#pragma unroll
        for (int nt = 0; nt < 2; ++nt) o[mt][nt] = (floatx4){0.f, 0.f, 0.f, 0.f};
    float m_r[2] = {-1e30f, -1e30f}, l_r[2] = {0.f, 0.f};

    const int sk_key = tid >> 3, sk_ch = tid & 7;
    const int sv_dim = tid & 63, sv_ch = tid >> 6;
    const bf16x8 zero8 = {0, 0, 0, 0, 0, 0, 0, 0};

    for (int tile = 0; tile < 13; ++tile) {
        const bool glob = (tile == 12);
        const int kbase = glob ? 0 : (c * WINSZ - WINSZ + tile * 32);

        __syncthreads();
        {
            int kpos = kbase + sk_key;
            bf16x8 val = zero8;
            if ((unsigned)kpos < (unsigned)S_LEN)
                val = *(const bf16x8*)(kh + (long)kpos * DH + sk_ch * 8);
            *(bf16x8*)(&Ks[sk_key * 72 + sk_ch * 8]) = val;
        }
        {
            int kc = kbase + sv_ch * 8;
            bf16x8 val = zero8;
            if (kc >= 0 && kc + 8 <= S_LEN)
                val = *(const bf16x8*)(vth + (long)sv_dim * S_LEN + kc);
            *(bf16x8*)(&Vs[sv_dim * 40 + sv_ch * 8]) = val;
        }
        __syncthreads();

        bf16x8 ak[2][2];
#pragma unroll
        for (int mt = 0; mt < 2; ++mt)
#pragma unroll
            for (int ks = 0; ks < 2; ++ks)
                ak[mt][ks] = *(const bf16x8*)(&Ks[(mt * 16 + ln15) * 72 + ks * 32 + ln4 * 8]);

        floatx4 s[2][2];
#pragma unroll
        for (int mt = 0; mt < 2; ++mt)
#pragma unroll
            for (int nt = 0; nt < 2; ++nt) {
                floatx4 acc = (floatx4){0.f, 0.f, 0.f, 0.f};
                acc = __builtin_amdgcn_mfma_f32_16x16x32_bf16(ak[mt][0], qf[nt][0], acc, 0, 0, 0);
                acc = __builtin_amdgcn_mfma_f32_16x16x32_bf16(ak[mt][1], qf[nt][1], acc, 0, 0, 0);
                s[mt][nt] = acc;
            }

#pragma unroll
        for (int mt = 0; mt < 2; ++mt) {
            const int kp0 = kbase + mt * 16 + ln4 * 4;
#pragma unroll
            for (int rg = 0; rg < 4; ++rg) {
                const int kpos = kp0 + rg;
                const bool kin = (unsigned)kpos < (unsigned)S_LEN;
                const float amv = kin ? amb[kpos] : 0.f;
#pragma unroll
                for (int nt = 0; nt < 2; ++nt) {
                    const int qpos = q0 + nt * 16 + ln15;
                    const int dlt = kpos > qpos ? kpos - qpos : qpos - kpos;
                    const bool valid = glob || (kpos >= NGLB && kin && dlt <= WINSZ);
                    s[mt][nt][rg] = valid ? s[mt][nt][rg] + amv : NEGV;
                }
            }
        }

        float alpha[2];
#pragma unroll
        for (int nt = 0; nt < 2; ++nt) {
            float mx = s[0][nt][0];
#pragma unroll
            for (int rg = 1; rg < 4; ++rg) mx = fmaxf(mx, s[0][nt][rg]);
#pragma unroll
            for (int rg = 0; rg < 4; ++rg) mx = fmaxf(mx, s[1][nt][rg]);
            mx = fmaxf(mx, __shfl_xor(mx, 16));
            mx = fmaxf(mx, __shfl_xor(mx, 32));
            const float mn = fmaxf(m_r[nt], mx);
            alpha[nt] = __expf(m_r[nt] - mn);
            m_r[nt] = mn;
        }

#pragma unroll
        for (int nt = 0; nt < 2; ++nt) {
            float sum = 0.f;
#pragma unroll
            for (int mt = 0; mt < 2; ++mt) {
                ushort4 pk;
#pragma unroll
                for (int rg = 0; rg < 4; ++rg) {
                    const float p = __expf(s[mt][nt][rg] - m_r[nt]);
                    sum += p;
                    ((unsigned short*)&pk)[rg] = f2bf(p);
                }
                *(ushort4*)(&Ps[wave][(nt * 16 + ln15) * 40 + mt * 16 + ln4 * 4]) = pk;
            }
            sum += __shfl_xor(sum, 16);
            sum += __shfl_xor(sum, 32);
            l_r[nt] = l_r[nt] * alpha[nt] + sum;
        }

#pragma unroll
        for (int mt = 0; mt < 4; ++mt)
#pragma unroll
            for (int nt = 0; nt < 2; ++nt)
#pragma unroll
                for (int rg = 0; rg < 4; ++rg) o[mt][nt][rg] *= alpha[nt];

        bf16x8 av[4], bp[2];
#pragma unroll
        for (int mt = 0; mt < 4; ++mt)
            av[mt] = *(const bf16x8*)(&Vs[(mt * 16 + ln15) * 40 + ln4 * 8]);
#pragma unroll
        for (int nt = 0; nt < 2; ++nt)
            bp[nt] = *(const bf16x8*)(&Ps[wave][(nt * 16 + ln15) * 40 + ln4 * 8]);
#pragma unroll
        for (int mt = 0; mt < 4; ++mt)
#pragma unroll
            for (int nt = 0; nt < 2; ++nt)
                o[mt][nt] = __builtin_amdgcn_mfma_f32_16x16x32_bf16(
                    av[mt], bp[nt], o[mt][nt], 0, 0, 0);
    }

    const float inv0 = 1.f / l_r[0], inv1 = 1.f / l_r[1];
#pragma unroll
    for (int nt = 0; nt < 2; ++nt) {
        const float inv = nt ? inv1 : inv0;
        const long row = (long)b * S_LEN + q0 + nt * 16 + ln15;
#pragma unroll
        for (int mt = 0; mt < 4; ++mt) {
            ushort4 ov;
#pragma unroll
            for (int rg = 0; rg < 4; ++rg)
                ((unsigned short*)&ov)[rg] = f2bf(o[mt][nt][rg] * inv);
            *(ushort4*)(ctx + row * D_MODEL + h * DH + mt * 16 + ln4 * 4) = ov;
        }
    }
}

// ---------------------------------------------------------------------------
// MFMA global-query attention. One block per (b,h); 8 waves x 512 keys/iter.
// ---------------------------------------------------------------------------
__global__ __launch_bounds__(512) void glob_mfma_k(
    const unsigned short* __restrict__ q, const unsigned short* __restrict__ k,
    const unsigned short* __restrict__ vt, const float* __restrict__ am,
    unsigned short* __restrict__ ctx)
{
    __shared__ unsigned short Ps[8][32 * 72];   // per wave [q=32][key=64+8pad]
    __shared__ float Om[64 * 36];               // merged O^T [dim][q]
    __shared__ float mW[8][32], lW[8][32], lTot[32];

    const int bh = blockIdx.x;                  // B*NH = 24
    const int b = bh / NHEAD, h = bh % NHEAD;
    const int tid = threadIdx.x;
    const int wave = tid >> 6, lane = tid & 63;
    const int ln15 = lane & 15, ln4 = lane >> 4;

    const unsigned short* kh  = k + (long)bh * S_LEN * DH;
    const unsigned short* vth = vt + (long)bh * DH * S_LEN;
    const float* amb = am + (long)b * S_LEN;

    bf16x8 qf[2][2];
#pragma unroll
    for (int nt = 0; nt < 2; ++nt)
#pragma unroll
        for (int ks = 0; ks < 2; ++ks)
            qf[nt][ks] = *(const bf16x8*)(q + ((long)bh * S_LEN + nt * 16 + ln15) * DH
                                          + ks * 32 + ln4 * 8);

    floatx4 o[4][2];
#pragma unroll
    for (int mt = 0; mt < 4; ++mt)
#pragma unroll
        for (int nt = 0; nt < 2; ++nt) o[mt][nt] = (floatx4){0.f, 0.f, 0.f, 0.f};
    float m_r[2] = {-1e30f, -1e30f}, l_r[2] = {0.f, 0.f};

    for (int it = 0; it < 8; ++it) {
        const int kbase = it * 512 + wave * 64;

        bf16x8 ak[4][2];
#pragma unroll
        for (int mt = 0; mt < 4; ++mt)
#pragma unroll
            for (int ks = 0; ks < 2; ++ks)
                ak[mt][ks] = *(const bf16x8*)(kh + (long)(kbase + mt * 16 + ln15) * DH
                                              + ks * 32 + ln4 * 8);

        floatx4 s[4][2];
#pragma unroll
        for (int mt = 0; mt < 4; ++mt)
#pragma unroll
            for (int nt = 0; nt < 2; ++nt) {
                floatx4 acc = (floatx4){0.f, 0.f, 0.f, 0.f};
                acc = __builtin_amdgcn_mfma_f32_16x16x32_bf16(ak[mt][0], qf[nt][0], acc, 0, 0, 0);
                acc = __builtin_amdgcn_mfma_f32_16x16x32_bf16(ak[mt][1], qf[nt][1], acc, 0, 0, 0);
                s[mt][nt] = acc;
            }

#pragma unroll
        for (int mt = 0; mt < 4; ++mt) {
            const int kp0 = kbase + mt * 16 + ln4 * 4;
#pragma unroll
            for (int rg = 0; rg < 4; ++rg) {
                const float amv = amb[kp0 + rg];
#pragma unroll
                for (int nt = 0; nt < 2; ++nt) s[mt][nt][rg] += amv;
            }
        }

        float alpha[2];
#pragma unroll
        for (int nt = 0; nt < 2; ++nt) {
            float mx = s[0][nt][0];
#pragma unroll
            for (int mt = 0; mt < 4; ++mt)
#pragma unroll
                for (int rg = 0; rg < 4; ++rg) mx = fmaxf(mx, s[mt][nt][rg]);
            mx = fmaxf(mx, __shfl_xor(mx, 16));
            mx = fmaxf(mx, __shfl_xor(mx, 32));
            const float mn = fmaxf(m_r[nt], mx);
            alpha[nt] = __expf(m_r[nt] - mn);
            m_r[nt] = mn;
        }

#pragma unroll
        for (int nt = 0; nt < 2; ++nt) {
            float sum = 0.f;
#pragma unroll
            for (int mt = 0; mt < 4; ++mt) {
                ushort4 pk;
#pragma unroll
                for (int rg = 0; rg < 4; ++rg) {
                    const float p = __expf(s[mt][nt][rg] - m_r[nt]);
                    sum += p;
                    ((unsigned short*)&pk)[rg] = f2bf(p);
                }
                *(ushort4*)(&Ps[wave][(nt * 16 + ln15) * 72 + mt * 16 + ln4 * 4]) = pk;
            }
            sum += __shfl_xor(sum, 16);
            sum += __shfl_xor(sum, 32);
            l_r[nt] = l_r[nt] * alpha[nt] + sum;
        }

#pragma unroll
        for (int mt = 0; mt < 4; ++mt)
#pragma unroll
            for (int nt = 0; nt < 2; ++nt)
#pragma unroll
                for (int rg = 0; rg < 4; ++rg) o[mt][nt][rg] *= alpha[nt];

        bf16x8 av[4][2], bp[2][2];
#pragma unroll
        for (int mt = 0; mt < 4; ++mt)
#pragma unroll
            for (int ks = 0; ks < 2; ++ks)
                av[mt][ks] = *(const bf16x8*)(vth + (long)(mt * 16 + ln15) * S_LEN
                                              + kbase + ks * 32 + ln4 * 8);
#pragma unroll
        for (int nt = 0; nt < 2; ++nt)
#pragma unroll
            for (int ks = 0; ks < 2; ++ks)
                bp[nt][ks] = *(const bf16x8*)(&Ps[wave][(nt * 16 + ln15) * 72
                                              + ks * 32 + ln4 * 8]);
#pragma unroll
        for (int mt = 0; mt < 4; ++mt)
#pragma unroll
            for (int nt = 0; nt < 2; ++nt) {
                o[mt][nt] = __builtin_amdgcn_mfma_f32_16x16x32_bf16(
                    av[mt][0], bp[nt][0], o[mt][nt], 0, 0, 0);
                o[mt][nt] = __builtin_amdgcn_mfma_f32_16x16x32_bf16(
                    av[mt][1], bp[nt][1], o[mt][nt], 0, 0, 0);
            }
    }

    if (ln4 == 0) {
#pragma unroll
        for (int nt = 0; nt < 2; ++nt) {
            mW[wave][nt * 16 + ln15] = m_r[nt];
            lW[wave][nt * 16 + ln15] = l_r[nt];
        }
    }
    for (int i = tid; i < 64 * 36; i += 512) Om[i] = 0.f;
    __syncthreads();

    float f[2];
#pragma unroll
    for (int nt = 0; nt < 2; ++nt) {
        const int qq = nt * 16 + ln15;
        float mt_ = mW[0][qq];
#pragma unroll
        for (int w = 1; w < 8; ++w) mt_ = fmaxf(mt_, mW[w][qq]);
        float lt = 0.f;
#pragma unroll
        for (int w = 0; w < 8; ++w) lt += __expf(mW[w][qq] - mt_) * lW[w][qq];
        f[nt] = __expf(m_r[nt] - mt_);
        if (wave == 0 && ln4 == 0) lTot[qq] = lt;
    }
#pragma unroll
    for (int mt = 0; mt < 4; ++mt)
#pragma unroll
        for (int nt = 0; nt < 2; ++nt)
#pragma unroll
            for (int rg = 0; rg < 4; ++rg) o[mt][nt][rg] *= f[nt];

    for (int wv = 0; wv < 8; ++wv) {
        if (wave == wv) {
#pragma unroll
            for (int mt = 0; mt < 4; ++mt)
#pragma unroll
                for (int nt = 0; nt < 2; ++nt)
#pragma unroll
                    for (int rg = 0; rg < 4; ++rg)
                        Om[(mt * 16 + ln4 * 4 + rg) * 36 + nt * 16 + ln15] += o[mt][nt][rg];
        }
        __syncthreads();
    }

    const int qq = tid >> 4, d0 = (tid & 15) * 4;
    const float inv = 1.f / lTot[qq];
    ushort4 ov;
#pragma unroll
    for (int i = 0; i < 4; ++i)
        ((unsigned short*)&ov)[i] = f2bf(Om[(d0 + i) * 36 + qq] * inv);
    *(ushort4*)(ctx + ((long)b * S_LEN + qq) * D_MODEL + h * DH + d0) = ov;
}

// ---------------------------------------------------------------------------
// LayerNorm rows of 768; optional bf16 copy.
// ---------------------------------------------------------------------------
__global__ __launch_bounds__(256) void ln_k(
    const float* __restrict__ in, float* __restrict__ out,
    unsigned short* __restrict__ out_bf,
    const float* __restrict__ gw, const float* __restrict__ bw)
{
    __shared__ float red[256];
    const long row = blockIdx.x;
    const float* x = in + row * D_MODEL;
    const int t = threadIdx.x;
    float v0 = x[t], v1 = x[t + 256], v2 = x[t + 512];

    red[t] = v0 + v1 + v2;
    __syncthreads();
    for (int off = 128; off; off >>= 1) {
        if (t < off) red[t] += red[t + off];
        __syncthreads();
    }
    const float mu = red[0] * (1.f / 768.f);
    __syncthreads();

    float d0 = v0 - mu, d1 = v1 - mu, d2 = v2 - mu;
    red[t] = d0 * d0 + d1 * d1 + d2 * d2;
    __syncthreads();
    for (int off = 128; off; off >>= 1) {
        if (t < off) red[t] += red[t + off];
        __syncthreads();
    }
    const float var = red[0] * (1.f / 768.f);
    const float rs = rsqrtf(var + 1e-12f);

    const float y0 = d0 * rs * gw[t] + bw[t];
    const float y1 = d1 * rs * gw[t + 256] + bw[t + 256];
    const float y2 = d2 * rs * gw[t + 512] + bw[t + 512];
    float* y = out + row * D_MODEL;
    y[t] = y0; y[t + 256] = y1; y[t + 512] = y2;
    if (out_bf) {
        unsigned short* yb = out_bf + row * D_MODEL;
        yb[t] = f2bf(y0); yb[t + 256] = f2bf(y1); yb[t + 512] = f2bf(y2);
    }
}

// ---------------------------------------------------------------------------
extern "C" void kernel_launch(void* const* d_in, const int* in_sizes, int n_in,
                              void* d_out, int out_size, void* d_ws, size_t ws_size,
                              hipStream_t stream)
{
    const float* hid  = (const float*)d_in[0];
    const float* am   = (const float*)d_in[1];
    const float* Wq   = (const float*)d_in[2];
    const float* bq   = (const float*)d_in[3];
    const float* Wk   = (const float*)d_in[4];
    const float* bk   = (const float*)d_in[5];
    const float* Wv   = (const float*)d_in[6];
    const float* bv   = (const float*)d_in[7];
    const float* Wo   = (const float*)d_in[8];
    const float* bo   = (const float*)d_in[9];
    const float* ln1g = (const float*)d_in[10];
    const float* ln1b = (const float*)d_in[11];
    const float* Wi   = (const float*)d_in[12];
    const float* bi   = (const float*)d_in[13];
    const float* Wo2  = (const float*)d_in[14];
    const float* bo2  = (const float*)d_in[15];
    const float* ln2g = (const float*)d_in[16];
    const float* ln2b = (const float*)d_in[17];

    const long M  = (long)B_SZ * S_LEN;                 // 8192
    const long NQ = NQC;                                // 6291456

    unsigned short* W16 = (unsigned short*)d_ws;
    unsigned short* qb   = W16;             // bf16 (B,NH,S,DH) — q|k|v contiguous
    unsigned short* kb   = W16 + NQ;
    unsigned short* vb   = W16 + 2 * NQ;
    unsigned short* vtb  = W16 + 3 * NQ;    // bf16 (B,NH,DH,S)
    unsigned short* ctxb = W16 + 4 * NQ;    // bf16 (B,S,768)
    unsigned short* hidb = W16 + 5 * NQ;    // bf16 hidden
    unsigned short* wqt  = W16 + 6 * NQ;    // [Wq|Wk|Wv]^T contiguous 2304x768
    unsigned short* wkt  = wqt + 589824;
    unsigned short* wvt  = wkt + 589824;
    unsigned short* wot  = wvt + 589824;
    unsigned short* wit  = wot + 589824;    // 2359296
    unsigned short* wo2t = wit + 2359296;   // 2359296 -> ends at 44826624
    float* tmp = (float*)(W16 + 44826624);  // attn_out fp32, 6291456 floats
                                            // -> ends at u16 57409536
    float* bcat = (float*)(W16 + 57409536); // 2304 fp32 concat bias (after tmp!)
    unsigned short* interb = W16;                        // over qb..vtb (4NQ)
    unsigned short* attnb  = hidb;                       // over hidb (dead)
    float* tmp2 = (float*)(W16 + 4 * NQ);                // over ctxb+hidb
    (void)ws_size; (void)in_sizes; (void)n_in; (void)out_size;

    transpose_k<<<dim3(24, 24), dim3(32, 8), 0, stream>>>(Wq, wqt, 768, 768);
    transpose_k<<<dim3(24, 24), dim3(32, 8), 0, stream>>>(Wk, wkt, 768, 768);
    transpose_k<<<dim3(24, 24), dim3(32, 8), 0, stream>>>(Wv, wvt, 768, 768);
    transpose_k<<<dim3(24, 24), dim3(32, 8), 0, stream>>>(Wo, wot, 768, 768);
    transpose_k<<<dim3(96, 24), dim3(32, 8), 0, stream>>>(Wi, wit, 768, 3072);
    transpose_k<<<dim3(24, 96), dim3(32, 8), 0, stream>>>(Wo2, wo2t, 3072, 768);
    conv_k<<<dim3((NQ / 4 + 255) / 256), dim3(256), 0, stream>>>(hid, hidb, NQ);
    bcat_k<<<dim3(9), dim3(256), 0, stream>>>(bq, bk, bv, bcat);

    dim3 blk(256);

    // fused QKV: one GEMM, N = 2304, scatter to qb/kb/vb
    gemm_bf<2><<<dim3(1152), blk, 0, stream>>>(hidb, wqt, bcat, nullptr, qb,
                                               M, 2304, 768, 18);

    vt_k<<<dim3(128, 24), blk, 0, stream>>>(vb, vtb);

    band_mfma_k<<<dim3(768), blk, 0, stream>>>(qb, kb, vtb, am, ctxb);
    glob_mfma_k<<<dim3(B_SZ * NHEAD), dim3(512), 0, stream>>>(qb, kb, vtb, am, ctxb);

    gemm_bf<0><<<dim3(384), blk, 0, stream>>>(ctxb, wot, bo, hid, tmp,
                                              M, 768, 768, 6);
    ln_k<<<dim3(M), blk, 0, stream>>>(tmp, tmp, attnb, ln1g, ln1b);

    gemm_bf<1><<<dim3(1536), blk, 0, stream>>>(attnb, wit, bi, nullptr, interb,
                                               M, 3072, 768, 24);

    gemm_bf<0><<<dim3(384), blk, 0, stream>>>(interb, wo2t, bo2, tmp, tmp2,
                                              M, 768, 3072, 6);
    ln_k<<<dim3(M), blk, 0, stream>>>(tmp2, (float*)d_out, nullptr, ln2g, ln2b);
}

// Round 8
// 458.993 us; speedup vs baseline: 5.8403x; 1.0323x over previous
//
#include <hip/hip_runtime.h>
#include <math.h>

#define NHEAD 12
#define DH 64
#define S_LEN 4096
#define B_SZ 2
#define D_MODEL 768
#define FF_DIM 3072
#define WINSZ 128
#define NGLB 32
#define NEGV -1e9f
#define NQC 6291456L

typedef __attribute__((ext_vector_type(8))) short bf16x8;
typedef __attribute__((ext_vector_type(4))) float floatx4;

__device__ __forceinline__ unsigned short f2bf(float x) {
    union { float f; unsigned u; } v; v.f = x;
    unsigned r = v.u + 0x7fffu + ((v.u >> 16) & 1u);
    return (unsigned short)(r >> 16);
}
__device__ __forceinline__ float bf2f(unsigned short x) {
    union { unsigned u; float f; } v; v.u = ((unsigned)x) << 16;
    return v.f;
}

__device__ __forceinline__ void async_copy16(const unsigned short* g, unsigned short* l) {
    __builtin_amdgcn_global_load_lds(
        (const __attribute__((address_space(1))) void*)g,
        (__attribute__((address_space(3))) void*)l, 16, 0, 0);
}

// ---------------------------------------------------------------------------
// fp32 -> bf16 elementwise
// ---------------------------------------------------------------------------
__global__ __launch_bounds__(256) void conv_k(
    const float* __restrict__ x, unsigned short* __restrict__ y, long n)
{
    long i = ((long)blockIdx.x * 256 + threadIdx.x) * 4;
    if (i >= n) return;
    float4 v = *(const float4*)(x + i);
    ushort4 o;
    o.x = f2bf(v.x); o.y = f2bf(v.y); o.z = f2bf(v.z); o.w = f2bf(v.w);
    *(ushort4*)(y + i) = o;
}

// ---------------------------------------------------------------------------
// concat 3 x 768 biases -> 2304
// ---------------------------------------------------------------------------
__global__ __launch_bounds__(256) void bcat_k(
    const float* __restrict__ a, const float* __restrict__ b,
    const float* __restrict__ c, float* __restrict__ o)
{
    int i = blockIdx.x * 256 + threadIdx.x;
    if (i < 768) o[i] = a[i];
    else if (i < 1536) o[i] = b[i - 768];
    else if (i < 2304) o[i] = c[i - 1536];
}

// ---------------------------------------------------------------------------
// W (KxN fp32) -> WT (NxK bf16)
// ---------------------------------------------------------------------------
__global__ __launch_bounds__(256) void transpose_k(
    const float* __restrict__ W, unsigned short* __restrict__ WT, int K, int N)
{
    __shared__ float tile[32][33];
    const int tx = threadIdx.x, ty = threadIdx.y;
    const int n0 = blockIdx.x * 32, k0 = blockIdx.y * 32;
#pragma unroll
    for (int i = 0; i < 4; ++i)
        tile[ty + 8 * i][tx] = W[(long)(k0 + ty + 8 * i) * N + n0 + tx];
    __syncthreads();
#pragma unroll
    for (int i = 0; i < 4; ++i)
        WT[(long)(n0 + ty + 8 * i) * K + k0 + tx] = f2bf(tile[tx][ty + 8 * i]);
}

// ---------------------------------------------------------------------------
// V (B,NH,S,DH) bf16 -> Vt (B,NH,DH,S) bf16
// ---------------------------------------------------------------------------
__global__ __launch_bounds__(256) void vt_k(
    const unsigned short* __restrict__ v, unsigned short* __restrict__ vt)
{
    const int bh = blockIdx.y;
    const int s0 = blockIdx.x * 32;
    const int w = threadIdx.x >> 6, lane = threadIdx.x & 63;
    const unsigned short* src = v + ((long)bh * S_LEN + s0 + w * 8) * DH + lane;
    unsigned short r[8];
#pragma unroll
    for (int j = 0; j < 8; ++j) r[j] = src[j * DH];
    unsigned short* dst = vt + ((long)bh * DH + lane) * S_LEN + s0 + w * 8;
    ushort4 lo, hi;
    lo.x = r[0]; lo.y = r[1]; lo.z = r[2]; lo.w = r[3];
    hi.x = r[4]; hi.y = r[5]; hi.z = r[6]; hi.w = r[7];
    *(ushort4*)dst = lo;
    *(ushort4*)(dst + 4) = hi;
}

// ---------------------------------------------------------------------------
// bf16 MFMA GEMM: C = epi(A @ BT^T + bias). XCD-clustered 1D swizzle.
// XOR LDS swizzle: staged chunk = (lane&3)^(srow&3) halves ds_read bank
// conflicts (8-way -> 4-way); read col = ((lane>>4)^(lane&3))*8.
// EPI 1: gelu -> bf16
// EPI 2: fused QKV scatter: part=n/768 (q|k|v), Q scaled by 0.125 -> bf16
// ---------------------------------------------------------------------------
template <int EPI>
__global__ __launch_bounds__(256) void gemm_bf(
    const unsigned short* __restrict__ A, const unsigned short* __restrict__ BT,
    const float* __restrict__ bias, void* __restrict__ out,
    int M, int N, int K, int nx)
{
    __shared__ unsigned short As[128 * 32];
    __shared__ unsigned short Bs[128 * 32];
    const int tid = threadIdx.x;
    const int wave = tid >> 6, lane = tid & 63;
    const int t8 = (blockIdx.x & 7) * (gridDim.x >> 3) + (blockIdx.x >> 3);
    const int m0 = (t8 / nx) * 128, n0 = (t8 % nx) * 128;
    const int wr = (wave >> 1) * 64, wc = (wave & 1) * 64;

    floatx4 acc[4][4];
#pragma unroll
    for (int i = 0; i < 4; ++i)
#pragma unroll
        for (int j = 0; j < 4; ++j) acc[i][j] = (floatx4){0.f, 0.f, 0.f, 0.f};

    const int srow = lane >> 2;
    const int schk = (((lane & 3) ^ (srow & 3))) * 8;   // XOR-swizzled stage
    const int r = lane & 15;
    const int q8 = ((lane >> 4) ^ (lane & 3)) * 8;      // XOR-swizzled read

    for (int k0 = 0; k0 < K; k0 += 32) {
#pragma unroll
        for (int gi = 0; gi < 2; ++gi) {
            const int g = wave * 2 + gi;
            async_copy16(A + (long)(m0 + g * 16 + srow) * K + k0 + schk, &As[g * 512]);
            async_copy16(BT + (long)(n0 + g * 16 + srow) * K + k0 + schk, &Bs[g * 512]);
        }
        __syncthreads();

        bf16x8 af[4], bfr[4];
#pragma unroll
        for (int i = 0; i < 4; ++i) {
            af[i]  = *(const bf16x8*)&As[(wr + i * 16 + r) * 32 + q8];
            bfr[i] = *(const bf16x8*)&Bs[(wc + i * 16 + r) * 32 + q8];
        }
#pragma unroll
        for (int i = 0; i < 4; ++i)
#pragma unroll
            for (int j = 0; j < 4; ++j)
                acc[i][j] = __builtin_amdgcn_mfma_f32_16x16x32_bf16(
                    af[i], bfr[j], acc[i][j], 0, 0, 0);
        __syncthreads();
    }

    const int col_l = lane & 15, row_l = (lane >> 4) * 4;
#pragma unroll
    for (int i = 0; i < 4; ++i) {
#pragma unroll
        for (int j = 0; j < 4; ++j) {
            const int n = n0 + wc + j * 16 + col_l;
            const float bv = bias[n];
#pragma unroll
            for (int rg = 0; rg < 4; ++rg) {
                const int m = m0 + wr + i * 16 + row_l + rg;
                float v = acc[i][j][rg] + bv;
                if (EPI == 1) {
                    v = 0.5f * v * (1.f + erff(v * 0.70710678118654752f));
                    ((unsigned short*)out)[(long)m * N + n] = f2bf(v);
                } else {
                    const int bb = m >> 12, s = m & 4095;
                    const int part = n / 768;          // 0=q, 1=k, 2=v
                    const int nn = n - part * 768;
                    const int hh = nn >> 6, dh = nn & 63;
                    const float sc = (part == 0) ? 0.125f : 1.f;
                    ((unsigned short*)out)[(long)part * NQC +
                        (((long)bb * NHEAD + hh) * S_LEN + s) * DH + dh] = f2bf(v * sc);
                }
            }
        }
    }
}

// ---------------------------------------------------------------------------
// Split-K (x2) bf16 MFMA GEMM: raw fp32 partials, no epilogue. Grid =
// 2*ntile blocks; t8 < ntile -> slice 0 (k in [0,K2)), else slice 1.
// Reduction happens inside ln2p_k.
// ---------------------------------------------------------------------------
__global__ __launch_bounds__(256) void gemm_sp(
    const unsigned short* __restrict__ A, const unsigned short* __restrict__ BT,
    float* __restrict__ p0, float* __restrict__ p1,
    int M, int N, int K2, int nx, int ntile)
{
    __shared__ unsigned short As[128 * 32];
    __shared__ unsigned short Bs[128 * 32];
    const int tid = threadIdx.x;
    const int wave = tid >> 6, lane = tid & 63;
    const int t8 = (blockIdx.x & 7) * (gridDim.x >> 3) + (blockIdx.x >> 3);
    const int slice = t8 >= ntile;
    const int tile = t8 - slice * ntile;
    const int m0 = (tile / nx) * 128, n0 = (tile % nx) * 128;
    const int kbeg = slice * K2, kend = kbeg + K2;
    float* P = slice ? p1 : p0;
    const int wr = (wave >> 1) * 64, wc = (wave & 1) * 64;

    floatx4 acc[4][4];
#pragma unroll
    for (int i = 0; i < 4; ++i)
#pragma unroll
        for (int j = 0; j < 4; ++j) acc[i][j] = (floatx4){0.f, 0.f, 0.f, 0.f};

    const int srow = lane >> 2;
    const int schk = (((lane & 3) ^ (srow & 3))) * 8;
    const int r = lane & 15;
    const int q8 = ((lane >> 4) ^ (lane & 3)) * 8;
    const long Kl = (long)K2 * 2;

    for (int k0 = kbeg; k0 < kend; k0 += 32) {
#pragma unroll
        for (int gi = 0; gi < 2; ++gi) {
            const int g = wave * 2 + gi;
            async_copy16(A + (long)(m0 + g * 16 + srow) * Kl + k0 + schk, &As[g * 512]);
            async_copy16(BT + (long)(n0 + g * 16 + srow) * Kl + k0 + schk, &Bs[g * 512]);
        }
        __syncthreads();

        bf16x8 af[4], bfr[4];
#pragma unroll
        for (int i = 0; i < 4; ++i) {
            af[i]  = *(const bf16x8*)&As[(wr + i * 16 + r) * 32 + q8];
            bfr[i] = *(const bf16x8*)&Bs[(wc + i * 16 + r) * 32 + q8];
        }
#pragma unroll
        for (int i = 0; i < 4; ++i)
#pragma unroll
            for (int j = 0; j < 4; ++j)
                acc[i][j] = __builtin_amdgcn_mfma_f32_16x16x32_bf16(
                    af[i], bfr[j], acc[i][j], 0, 0, 0);
        __syncthreads();
    }

    const int col_l = lane & 15, row_l = (lane >> 4) * 4;
#pragma unroll
    for (int i = 0; i < 4; ++i)
#pragma unroll
        for (int j = 0; j < 4; ++j) {
            const int n = n0 + wc + j * 16 + col_l;
#pragma unroll
            for (int rg = 0; rg < 4; ++rg) {
                const int m = m0 + wr + i * 16 + row_l + rg;
                P[(long)m * N + n] = acc[i][j][rg];
            }
        }
}

// ---------------------------------------------------------------------------
// MFMA band attention. One block per (b,h,chunk); 4 waves x 32 queries.
// ---------------------------------------------------------------------------
__global__ __launch_bounds__(256) void band_mfma_k(
    const unsigned short* __restrict__ q, const unsigned short* __restrict__ k,
    const unsigned short* __restrict__ vt, const float* __restrict__ am,
    unsigned short* __restrict__ ctx)
{
    __shared__ unsigned short Ks[32 * 72];
    __shared__ unsigned short Vs[64 * 40];
    __shared__ unsigned short Ps[4][32 * 40];

    const int blk = blockIdx.x;
    const int c = blk & 31;
    const int h = (blk >> 5) % NHEAD;
    const int b = blk / (32 * NHEAD);
    const int tid = threadIdx.x;
    const int wave = tid >> 6, lane = tid & 63;
    const long bh = (long)b * NHEAD + h;

    const unsigned short* kh  = k + bh * S_LEN * DH;
    const unsigned short* vth = vt + bh * (long)DH * S_LEN;
    const float* amb = am + (long)b * S_LEN;

    const int q0 = c * WINSZ + wave * 32;
    const int ln15 = lane & 15, ln4 = lane >> 4;

    bf16x8 qf[2][2];
#pragma unroll
    for (int nt = 0; nt < 2; ++nt)
#pragma unroll
        for (int ks = 0; ks < 2; ++ks)
            qf[nt][ks] = *(const bf16x8*)(q + (bh * S_LEN + q0 + nt * 16 + ln15) * DH
                                          + ks * 32 + ln4 * 8);

    floatx4 o[4][2];
#pragma unroll
    for (int mt = 0; mt < 4; ++mt)
#pragma unroll
        for (int nt = 0; nt < 2; ++nt) o[mt][nt] = (floatx4){0.f, 0.f, 0.f, 0.f};
    float m_r[2] = {-1e30f, -1e30f}, l_r[2] = {0.f, 0.f};

    const int sk_key = tid >> 3, sk_ch = tid & 7;
    const int sv_dim = tid & 63, sv_ch = tid >> 6;
    const bf16x8 zero8 = {0, 0, 0, 0, 0, 0, 0, 0};

    for (int tile = 0; tile < 13; ++tile) {
        const bool glob = (tile == 12);
        const int kbase = glob ? 0 : (c * WINSZ - WINSZ + tile * 32);

        __syncthreads();
        {
            int kpos = kbase + sk_key;
            bf16x8 val = zero8;
            if ((unsigned)kpos < (unsigned)S_LEN)
                val = *(const bf16x8*)(kh + (long)kpos * DH + sk_ch * 8);
            *(bf16x8*)(&Ks[sk_key * 72 + sk_ch * 8]) = val;
        }
        {
            int kc = kbase + sv_ch * 8;
            bf16x8 val = zero8;
            if (kc >= 0 && kc + 8 <= S_LEN)
                val = *(const bf16x8*)(vth + (long)sv_dim * S_LEN + kc);
            *(bf16x8*)(&Vs[sv_dim * 40 + sv_ch * 8]) = val;
        }
        __syncthreads();

        bf16x8 ak[2][2];
#pragma unroll
        for (int mt = 0; mt < 2; ++mt)
#pragma unroll
            for (int ks = 0; ks < 2; ++ks)
                ak[mt][ks] = *(const bf16x8*)(&Ks[(mt * 16 + ln15) * 72 + ks * 32 + ln4 * 8]);

        floatx4 s[2][2];
#pragma unroll
        for (int mt = 0; mt < 2; ++mt)
#pragma unroll
            for (int nt = 0; nt < 2; ++nt) {
                floatx4 acc = (floatx4){0.f, 0.f, 0.f, 0.f};
                acc = __builtin_amdgcn_mfma_f32_16x16x32_bf16(ak[mt][0], qf[nt][0], acc, 0, 0, 0);
                acc = __builtin_amdgcn_mfma_f32_16x16x32_bf16(ak[mt][1], qf[nt][1], acc, 0, 0, 0);
                s[mt][nt] = acc;
            }

#pragma unroll
        for (int mt = 0; mt < 2; ++mt) {
            const int kp0 = kbase + mt * 16 + ln4 * 4;
#pragma unroll
            for (int rg = 0; rg < 4; ++rg) {
                const int kpos = kp0 + rg;
                const bool kin = (unsigned)kpos < (unsigned)S_LEN;
                const float amv = kin ? amb[kpos] : 0.f;
#pragma unroll
                for (int nt = 0; nt < 2; ++nt) {
                    const int qpos = q0 + nt * 16 + ln15;
                    const int dlt = kpos > qpos ? kpos - qpos : qpos - kpos;
                    const bool valid = glob || (kpos >= NGLB && kin && dlt <= WINSZ);
                    s[mt][nt][rg] = valid ? s[mt][nt][rg] + amv : NEGV;
                }
            }
        }

        float alpha[2];
#pragma unroll
        for (int nt = 0; nt < 2; ++nt) {
            float mx = s[0][nt][0];
#pragma unroll
            for (int rg = 1; rg < 4; ++rg) mx = fmaxf(mx, s[0][nt][rg]);
#pragma unroll
            for (int rg = 0; rg < 4; ++rg) mx = fmaxf(mx, s[1][nt][rg]);
            mx = fmaxf(mx, __shfl_xor(mx, 16));
            mx = fmaxf(mx, __shfl_xor(mx, 32));
            const float mn = fmaxf(m_r[nt], mx);
            alpha[nt] = __expf(m_r[nt] - mn);
            m_r[nt] = mn;
        }

#pragma unroll
        for (int nt = 0; nt < 2; ++nt) {
            float sum = 0.f;
#pragma unroll
            for (int mt = 0; mt < 2; ++mt) {
                ushort4 pk;
#pragma unroll
                for (int rg = 0; rg < 4; ++rg) {
                    const float p = __expf(s[mt][nt][rg] - m_r[nt]);
                    sum += p;
                    ((unsigned short*)&pk)[rg] = f2bf(p);
                }
                *(ushort4*)(&Ps[wave][(nt * 16 + ln15) * 40 + mt * 16 + ln4 * 4]) = pk;
            }
            sum += __shfl_xor(sum, 16);
            sum += __shfl_xor(sum, 32);
            l_r[nt] = l_r[nt] * alpha[nt] + sum;
        }

#pragma unroll
        for (int mt = 0; mt < 4; ++mt)
#pragma unroll
            for (int nt = 0; nt < 2; ++nt)
#pragma unroll
                for (int rg = 0; rg < 4; ++rg) o[mt][nt][rg] *= alpha[nt];

        bf16x8 av[4], bp[2];
#pragma unroll
        for (int mt = 0; mt < 4; ++mt)
            av[mt] = *(const bf16x8*)(&Vs[(mt * 16 + ln15) * 40 + ln4 * 8]);
#pragma unroll
        for (int nt = 0; nt < 2; ++nt)
            bp[nt] = *(const bf16x8*)(&Ps[wave][(nt * 16 + ln15) * 40 + ln4 * 8]);
#pragma unroll
        for (int mt = 0; mt < 4; ++mt)
#pragma unroll
            for (int nt = 0; nt < 2; ++nt)
                o[mt][nt] = __builtin_amdgcn_mfma_f32_16x16x32_bf16(
                    av[mt], bp[nt], o[mt][nt], 0, 0, 0);
    }

    const float inv0 = 1.f / l_r[0], inv1 = 1.f / l_r[1];
#pragma unroll
    for (int nt = 0; nt < 2; ++nt) {
        const float inv = nt ? inv1 : inv0;
        const long row = (long)b * S_LEN + q0 + nt * 16 + ln15;
#pragma unroll
        for (int mt = 0; mt < 4; ++mt) {
            ushort4 ov;
#pragma unroll
            for (int rg = 0; rg < 4; ++rg)
                ((unsigned short*)&ov)[rg] = f2bf(o[mt][nt][rg] * inv);
            *(ushort4*)(ctx + row * D_MODEL + h * DH + mt * 16 + ln4 * 4) = ov;
        }
    }
}

// ---------------------------------------------------------------------------
// MFMA global-query attention. One block per (b,h); 8 waves x 512 keys/iter.
// ---------------------------------------------------------------------------
__global__ __launch_bounds__(512) void glob_mfma_k(
    const unsigned short* __restrict__ q, const unsigned short* __restrict__ k,
    const unsigned short* __restrict__ vt, const float* __restrict__ am,
    unsigned short* __restrict__ ctx)
{
    __shared__ unsigned short Ps[8][32 * 72];
    __shared__ float Om[64 * 36];
    __shared__ float mW[8][32], lW[8][32], lTot[32];

    const int bh = blockIdx.x;
    const int b = bh / NHEAD, h = bh % NHEAD;
    const int tid = threadIdx.x;
    const int wave = tid >> 6, lane = tid & 63;
    const int ln15 = lane & 15, ln4 = lane >> 4;

    const unsigned short* kh  = k + (long)bh * S_LEN * DH;
    const unsigned short* vth = vt + (long)bh * DH * S_LEN;
    const float* amb = am + (long)b * S_LEN;

    bf16x8 qf[2][2];
#pragma unroll
    for (int nt = 0; nt < 2; ++nt)
#pragma unroll
        for (int ks = 0; ks < 2; ++ks)
            qf[nt][ks] = *(const bf16x8*)(q + ((long)bh * S_LEN + nt * 16 + ln15) * DH
                                          + ks * 32 + ln4 * 8);

    floatx4 o[4][2];
#pragma unroll
    for (int mt = 0; mt < 4; ++mt)
#pragma unroll
        for (int nt = 0; nt < 2; ++nt) o[mt][nt] = (floatx4){0.f, 0.f, 0.f, 0.f};
    float m_r[2] = {-1e30f, -1e30f}, l_r[2] = {0.f, 0.f};

    for (int it = 0; it < 8; ++it) {
        const int kbase = it * 512 + wave * 64;

        bf16x8 ak[4][2];
#pragma unroll
        for (int mt = 0; mt < 4; ++mt)
#pragma unroll
            for (int ks = 0; ks < 2; ++ks)
                ak[mt][ks] = *(const bf16x8*)(kh + (long)(kbase + mt * 16 + ln15) * DH
                                              + ks * 32 + ln4 * 8);

        floatx4 s[4][2];
#pragma unroll
        for (int mt = 0; mt < 4; ++mt)
#pragma unroll
            for (int nt = 0; nt < 2; ++nt) {
                floatx4 acc = (floatx4){0.f, 0.f, 0.f, 0.f};
                acc = __builtin_amdgcn_mfma_f32_16x16x32_bf16(ak[mt][0], qf[nt][0], acc, 0, 0, 0);
                acc = __builtin_amdgcn_mfma_f32_16x16x32_bf16(ak[mt][1], qf[nt][1], acc, 0, 0, 0);
                s[mt][nt] = acc;
            }

#pragma unroll
        for (int mt = 0; mt < 4; ++mt) {
            const int kp0 = kbase + mt * 16 + ln4 * 4;
#pragma unroll
            for (int rg = 0; rg < 4; ++rg) {
                const float amv = amb[kp0 + rg];
#pragma unroll
                for (int nt = 0; nt < 2; ++nt) s[mt][nt][rg] += amv;
            }
        }

        float alpha[2];
#pragma unroll
        for (int nt = 0; nt < 2; ++nt) {
            float mx = s[0][nt][0];
#pragma unroll
            for (int mt = 0; mt < 4; ++mt)
#pragma unroll
                for (int rg = 0; rg < 4; ++rg) mx = fmaxf(mx, s[mt][nt][rg]);
            mx = fmaxf(mx, __shfl_xor(mx, 16));
            mx = fmaxf(mx, __shfl_xor(mx, 32));
            const float mn = fmaxf(m_r[nt], mx);
            alpha[nt] = __expf(m_r[nt] - mn);
            m_r[nt] = mn;
        }

#pragma unroll
        for (int nt = 0; nt < 2; ++nt) {
            float sum = 0.f;
#pragma unroll
            for (int mt = 0; mt < 4; ++mt) {
                ushort4 pk;
#pragma unroll
                for (int rg = 0; rg < 4; ++rg) {
                    const float p = __expf(s[mt][nt][rg] - m_r[nt]);
                    sum += p;
                    ((unsigned short*)&pk)[rg] = f2bf(p);
                }
                *(ushort4*)(&Ps[wave][(nt * 16 + ln15) * 72 + mt * 16 + ln4 * 4]) = pk;
            }
            sum += __shfl_xor(sum, 16);
            sum += __shfl_xor(sum, 32);
            l_r[nt] = l_r[nt] * alpha[nt] + sum;
        }

#pragma unroll
        for (int mt = 0; mt < 4; ++mt)
#pragma unroll
            for (int nt = 0; nt < 2; ++nt)
#pragma unroll
                for (int rg = 0; rg < 4; ++rg) o[mt][nt][rg] *= alpha[nt];

        bf16x8 av[4][2], bp[2][2];
#pragma unroll
        for (int mt = 0; mt < 4; ++mt)
#pragma unroll
            for (int ks = 0; ks < 2; ++ks)
                av[mt][ks] = *(const bf16x8*)(vth + (long)(mt * 16 + ln15) * S_LEN
                                              + kbase + ks * 32 + ln4 * 8);
#pragma unroll
        for (int nt = 0; nt < 2; ++nt)
#pragma unroll
            for (int ks = 0; ks < 2; ++ks)
                bp[nt][ks] = *(const bf16x8*)(&Ps[wave][(nt * 16 + ln15) * 72
                                              + ks * 32 + ln4 * 8]);
#pragma unroll
        for (int mt = 0; mt < 4; ++mt)
#pragma unroll
            for (int nt = 0; nt < 2; ++nt) {
                o[mt][nt] = __builtin_amdgcn_mfma_f32_16x16x32_bf16(
                    av[mt][0], bp[nt][0], o[mt][nt], 0, 0, 0);
                o[mt][nt] = __builtin_amdgcn_mfma_f32_16x16x32_bf16(
                    av[mt][1], bp[nt][1], o[mt][nt], 0, 0, 0);
            }
    }

    if (ln4 == 0) {
#pragma unroll
        for (int nt = 0; nt < 2; ++nt) {
            mW[wave][nt * 16 + ln15] = m_r[nt];
            lW[wave][nt * 16 + ln15] = l_r[nt];
        }
    }
    for (int i = tid; i < 64 * 36; i += 512) Om[i] = 0.f;
    __syncthreads();

    float f[2];
#pragma unroll
    for (int nt = 0; nt < 2; ++nt) {
        const int qq = nt * 16 + ln15;
        float mt_ = mW[0][qq];
#pragma unroll
        for (int w = 1; w < 8; ++w) mt_ = fmaxf(mt_, mW[w][qq]);
        float lt = 0.f;
#pragma unroll
        for (int w = 0; w < 8; ++w) lt += __expf(mW[w][qq] - mt_) * lW[w][qq];
        f[nt] = __expf(m_r[nt] - mt_);
        if (wave == 0 && ln4 == 0) lTot[qq] = lt;
    }
#pragma unroll
    for (int mt = 0; mt < 4; ++mt)
#pragma unroll
        for (int nt = 0; nt < 2; ++nt)
#pragma unroll
            for (int rg = 0; rg < 4; ++rg) o[mt][nt][rg] *= f[nt];

    for (int wv = 0; wv < 8; ++wv) {
        if (wave == wv) {
#pragma unroll
            for (int mt = 0; mt < 4; ++mt)
#pragma unroll
                for (int nt = 0; nt < 2; ++nt)
#pragma unroll
                    for (int rg = 0; rg < 4; ++rg)
                        Om[(mt * 16 + ln4 * 4 + rg) * 36 + nt * 16 + ln15] += o[mt][nt][rg];
        }
        __syncthreads();
    }

    const int qq = tid >> 4, d0 = (tid & 15) * 4;
    const float inv = 1.f / lTot[qq];
    ushort4 ov;
#pragma unroll
    for (int i = 0; i < 4; ++i)
        ((unsigned short*)&ov)[i] = f2bf(Om[(d0 + i) * 36 + qq] * inv);
    *(ushort4*)(ctx + ((long)b * S_LEN + qq) * D_MODEL + h * DH + d0) = ov;
}

// ---------------------------------------------------------------------------
// Fused split-K reduce + bias + residual + LayerNorm. x = p0+p1+bias+resid.
// One block per row (768 cols). Optional bf16 copy.
// ---------------------------------------------------------------------------
__global__ __launch_bounds__(256) void ln2p_k(
    const float* __restrict__ p0, const float* __restrict__ p1,
    const float* __restrict__ bias, const float* __restrict__ resid,
    float* __restrict__ out, unsigned short* __restrict__ out_bf,
    const float* __restrict__ gw, const float* __restrict__ bw)
{
    __shared__ float red[256];
    const long row = blockIdx.x;
    const long base = row * D_MODEL;
    const int t = threadIdx.x;
    float v0 = p0[base + t]       + p1[base + t]       + bias[t]       + resid[base + t];
    float v1 = p0[base + t + 256] + p1[base + t + 256] + bias[t + 256] + resid[base + t + 256];
    float v2 = p0[base + t + 512] + p1[base + t + 512] + bias[t + 512] + resid[base + t + 512];

    red[t] = v0 + v1 + v2;
    __syncthreads();
    for (int off = 128; off; off >>= 1) {
        if (t < off) red[t] += red[t + off];
        __syncthreads();
    }
    const float mu = red[0] * (1.f / 768.f);
    __syncthreads();

    float d0 = v0 - mu, d1 = v1 - mu, d2 = v2 - mu;
    red[t] = d0 * d0 + d1 * d1 + d2 * d2;
    __syncthreads();
    for (int off = 128; off; off >>= 1) {
        if (t < off) red[t] += red[t + off];
        __syncthreads();
    }
    const float var = red[0] * (1.f / 768.f);
    const float rs = rsqrtf(var + 1e-12f);

    const float y0 = d0 * rs * gw[t] + bw[t];
    const float y1 = d1 * rs * gw[t + 256] + bw[t + 256];
    const float y2 = d2 * rs * gw[t + 512] + bw[t + 512];
    if (out) {
        float* y = out + base;
        y[t] = y0; y[t + 256] = y1; y[t + 512] = y2;
    }
    if (out_bf) {
        unsigned short* yb = out_bf + base;
        yb[t] = f2bf(y0); yb[t + 256] = f2bf(y1); yb[t + 512] = f2bf(y2);
    }
}

// ---------------------------------------------------------------------------
extern "C" void kernel_launch(void* const* d_in, const int* in_sizes, int n_in,
                              void* d_out, int out_size, void* d_ws, size_t ws_size,
                              hipStream_t stream)
{
    const float* hid  = (const float*)d_in[0];
    const float* am   = (const float*)d_in[1];
    const float* Wq   = (const float*)d_in[2];
    const float* bq   = (const float*)d_in[3];
    const float* Wk   = (const float*)d_in[4];
    const float* bk   = (const float*)d_in[5];
    const float* Wv   = (const float*)d_in[6];
    const float* bv   = (const float*)d_in[7];
    const float* Wo   = (const float*)d_in[8];
    const float* bo   = (const float*)d_in[9];
    const float* ln1g = (const float*)d_in[10];
    const float* ln1b = (const float*)d_in[11];
    const float* Wi   = (const float*)d_in[12];
    const float* bi   = (const float*)d_in[13];
    const float* Wo2  = (const float*)d_in[14];
    const float* bo2  = (const float*)d_in[15];
    const float* ln2g = (const float*)d_in[16];
    const float* ln2b = (const float*)d_in[17];

    const long M  = (long)B_SZ * S_LEN;                 // 8192
    const long NQ = NQC;                                // 6291456

    unsigned short* W16 = (unsigned short*)d_ws;
    unsigned short* qb   = W16;             // bf16 (B,NH,S,DH) — q|k|v contiguous
    unsigned short* kb   = W16 + NQ;
    unsigned short* vb   = W16 + 2 * NQ;
    unsigned short* vtb  = W16 + 3 * NQ;    // bf16 (B,NH,DH,S)
    unsigned short* ctxb = W16 + 4 * NQ;    // bf16 (B,S,768)
    unsigned short* hidb = W16 + 5 * NQ;    // bf16 hidden
    unsigned short* wqt  = W16 + 6 * NQ;    // [Wq|Wk|Wv]^T contiguous 2304x768
    unsigned short* wkt  = wqt + 589824;
    unsigned short* wvt  = wkt + 589824;
    unsigned short* wot  = wvt + 589824;
    unsigned short* wit  = wot + 589824;    // 2359296
    unsigned short* wo2t = wit + 2359296;   // 2359296 -> ends at u16 44826624
    float* tmp   = (float*)(W16 + 44826624);  // attn_out fp32 -> ends u16 57409536
    float* partB1 = (float*)(W16 + 57409536); // Wo2 split slice1 -> ends u16 69992448
    float* bcat  = (float*)(W16 + 69992448);  // 2304 fp32
    // aliases over dead regions:
    float* partA0 = (float*)W16;                  // Wo slice0 (over qb,kb)
    float* partA1 = (float*)(W16 + 2 * NQ);       // Wo slice1 (over vb,vtb)
    unsigned short* interb = W16;                 // Wi out (over qb..vtb)
    unsigned short* attnb  = hidb;                // LN1 bf16 (over hidb)
    float* partB0 = (float*)(W16 + 4 * NQ);       // Wo2 slice0 (over ctxb,hidb)
    (void)ws_size; (void)in_sizes; (void)n_in; (void)out_size;

    transpose_k<<<dim3(24, 24), dim3(32, 8), 0, stream>>>(Wq, wqt, 768, 768);
    transpose_k<<<dim3(24, 24), dim3(32, 8), 0, stream>>>(Wk, wkt, 768, 768);
    transpose_k<<<dim3(24, 24), dim3(32, 8), 0, stream>>>(Wv, wvt, 768, 768);
    transpose_k<<<dim3(24, 24), dim3(32, 8), 0, stream>>>(Wo, wot, 768, 768);
    transpose_k<<<dim3(96, 24), dim3(32, 8), 0, stream>>>(Wi, wit, 768, 3072);
    transpose_k<<<dim3(24, 96), dim3(32, 8), 0, stream>>>(Wo2, wo2t, 3072, 768);
    conv_k<<<dim3((NQ / 4 + 255) / 256), dim3(256), 0, stream>>>(hid, hidb, NQ);
    bcat_k<<<dim3(9), dim3(256), 0, stream>>>(bq, bk, bv, bcat);

    dim3 blk(256);

    // fused QKV: one GEMM, N = 2304, scatter to qb/kb/vb
    gemm_bf<2><<<dim3(1152), blk, 0, stream>>>(hidb, wqt, bcat, qb,
                                               M, 2304, 768, 18);

    vt_k<<<dim3(128, 24), blk, 0, stream>>>(vb, vtb);

    band_mfma_k<<<dim3(768), blk, 0, stream>>>(qb, kb, vtb, am, ctxb);
    glob_mfma_k<<<dim3(B_SZ * NHEAD), dim3(512), 0, stream>>>(qb, kb, vtb, am, ctxb);

    // Wo split-K x2 -> partA0/partA1 ; LN1 fuses reduce+bias+resid
    gemm_sp<<<dim3(768), blk, 0, stream>>>(ctxb, wot, partA0, partA1,
                                           M, 768, 384, 6, 384);
    ln2p_k<<<dim3(M), blk, 0, stream>>>(partA0, partA1, bo, hid,
                                        tmp, attnb, ln1g, ln1b);

    // inter = gelu(attn_out @ Wi + bi)
    gemm_bf<1><<<dim3(1536), blk, 0, stream>>>(attnb, wit, bi, interb,
                                               M, 3072, 768, 24);

    // Wo2 split-K x2 -> partB0/partB1 ; LN2 fuses reduce+bias+resid
    gemm_sp<<<dim3(768), blk, 0, stream>>>(interb, wo2t, partB0, partB1,
                                           M, 768, 1536, 6, 384);
    ln2p_k<<<dim3(M), blk, 0, stream>>>(partB0, partB1, bo2, tmp,
                                        (float*)d_out, nullptr, ln2g, ln2b);
}